// Round 22
// baseline (331.436 us; speedup 1.0000x reference)
//
#include <hip/hip_runtime.h>
#include <hip/hip_bf16.h>

typedef unsigned short u16;
typedef unsigned int u32;

#define DEVI __device__ __forceinline__

constexpr int BB = 8, HHc = 56, WWc = 56, DIMC = 384, NHC = 8, HDC = 48, WSZ = 14;
constexpr int NTOK = BB * HHc * WWc;          // 25088
constexpr int HIDC = 4 * DIMC;                // 1536
constexpr float EPSF = 1e-5f;
constexpr float SCALEF = 0.14433756729740643f;   // 48^-0.5
constexpr float LOG2E = 1.4426950408889634f;

typedef short bf16x8 __attribute__((ext_vector_type(8)));
typedef float f32x4 __attribute__((ext_vector_type(4)));

// ---- bf16 helpers (raw ushort view) ----
DEVI float b2f(u16 u) { u32 x = ((u32)u) << 16; float f; __builtin_memcpy(&f, &x, 4); return f; }
DEVI float uasf(u32 x) { float f; __builtin_memcpy(&f, &x, 4); return f; }
DEVI u16 f2b(float f) {
  u32 x; __builtin_memcpy(&x, &f, 4);
  u32 r = (x >> 16) & 1u; x += 0x7fffu + r;
  return (u16)(x >> 16);
}

DEVI float wred_sum(float v) {
  #pragma unroll
  for (int o = 32; o; o >>= 1) v += __shfl_xor(v, o);
  return v;
}

// async global->LDS, 16B per lane; dest = uniform base + lane*16
#define GLOAD_LDS16(g, l) __builtin_amdgcn_global_load_lds( \
    (const __attribute__((address_space(1))) u32*)(g), \
    (__attribute__((address_space(3))) u32*)(l), 16, 0, 0)

#define MFMA16(a, b, c) __builtin_amdgcn_mfma_f32_16x16x32_bf16((a), (b), (c), 0, 0, 0)

// ---- weight convert f32 [K][N] -> bf16 [N][K], LDS-tiled transpose ----
__global__ __launch_bounds__(256)
void wcvt_kernel(const float* __restrict__ in, u16* __restrict__ out, int K, int N) {
  __shared__ float t[32][33];
  int bk = blockIdx.x * 32, bn = blockIdx.y * 32;
  int tx = threadIdx.x & 31, ty = threadIdx.x >> 5;
  #pragma unroll
  for (int i = 0; i < 32; i += 8)
    t[ty + i][tx] = in[(size_t)(bk + ty + i) * N + bn + tx];
  __syncthreads();
  #pragma unroll
  for (int i = 0; i < 32; i += 8)
    out[(size_t)(bn + ty + i) * K + bk + tx] = f2b(t[tx][ty + i]);
}

// ---- LayerNorm over 384: f32 in -> bf16 out, K-BLOCKED [12][NTOK][32] ----
__global__ __launch_bounds__(256)
void ln384_kernel(const float* __restrict__ x, const float* __restrict__ w,
                  const float* __restrict__ b, u16* __restrict__ out) {
  int wave = threadIdx.x >> 6, lane = threadIdx.x & 63;
  int tok = blockIdx.x * 4 + wave;
  if (tok >= NTOK) return;
  const float* xr = x + (size_t)tok * DIMC;
  float v[6]; float s = 0.f, ss = 0.f;
  #pragma unroll
  for (int i = 0; i < 6; ++i) {
    v[i] = xr[lane + i * 64];
    s += v[i]; ss += v[i] * v[i];
  }
  s = wred_sum(s); ss = wred_sum(ss);
  float mean = s * (1.f / 384.f);
  float var = ss * (1.f / 384.f) - mean * mean;
  float inv = rsqrtf(var + EPSF);
  #pragma unroll
  for (int i = 0; i < 6; ++i) {
    int c = lane + i * 64;
    out[(size_t)(c >> 5) * (NTOK * 32) + (size_t)tok * 32 + (c & 31)] =
        f2b((v[i] - mean) * inv * w[c] + b[c]);
  }
}

// ---- MFMA GEMM: C[M,N] = A(bf16, K-BLOCKED [K/32][M][32]) @ Wt^T + bias ----
// 128xBN tile, BK=32, 4 waves; 2-buffer LDS, TWO barriers per k-step
// (STAGE -> vmcnt(counted) -> barrier publishes all waves' loads;
//  reads+MFMA -> lgkm(0) -> barrier protects buffer overwrite).
// vmcnt is PER-WAVE: barrier must come AFTER the vmcnt (r18 race lesson).
// Flat grid, col-fastest + chunked XCD swizzle; MODE 0/2 bf16 out via
// LDS-staged coalesced epilogue.
template<int MODE, int BN>
__global__ __launch_bounds__(256)
void mgemm_kernel(const u16* __restrict__ A, const u16* __restrict__ Wt,
                  const float* __restrict__ bias, const float* __restrict__ res,
                  void* __restrict__ outv, int M, int N, int K) {
  constexpr int FN = BN / 32;                    // col frags per wave (4 or 2)
  constexpr int ASZ = 2 * 128 * 32;              // u16; 2 A buffers
  constexpr int BSZ = 2 * BN * 32;               // u16; 2 B buffers
  __shared__ __attribute__((aligned(16))) u16 SM[ASZ + BSZ];
  // ---- chunked XCD swizzle ----
  int nblk = gridDim.x;
  int qch = nblk >> 3, rch = nblk & 7;
  int orig = blockIdx.x;
  int xcd = orig & 7, off = orig >> 3;
  int tile = ((xcd < rch) ? xcd * (qch + 1) : rch * (qch + 1) + (xcd - rch) * qch) + off;
  int ncol = N / BN;
  int brow = tile / ncol, bcol = tile - brow * ncol;   // col-fastest
  int bm0 = brow * 128, bn0 = bcol * BN;
  int tid = threadIdx.x;
  int wave = tid >> 6, lane = tid & 63;
  int wr = wave >> 1, wc = wave & 1;
  int lrow = lane >> 2;
  int slot = (lane & 3) ^ ((lane >> 3) & 3);
  const size_t slab = (size_t)M * 32;            // one k-slab of A
  const u16* ag0 = A + (size_t)(bm0 + wave * 32 + lrow) * 32 + slot * 8;
  const u16* ag1 = ag0 + 16 * 32;
  const u16* bg0 = Wt + (size_t)(bn0 + wave * (BN / 4) + lrow) * K + slot * 8;
  const u16* bg1 = bg0 + (size_t)16 * K;         // used only when BN==128
  int q4 = lane >> 4, r16 = lane & 15;
  int rslot = (q4 ^ ((r16 >> 1) & 3)) * 8;       // de-swizzle on read
  int aoff = (wr * 64 + r16) * 32 + rslot;
  int boff = (wc * (BN / 2) + r16) * 32 + rslot;
  f32x4 acc[4][FN] = {};
  int nk = K >> 5;
  {  // prologue: stage tile 0 into buf 0
    u16* a0 = SM + wave * 1024;
    u16* b0 = SM + ASZ + wave * (BN / 4) * 32;
    GLOAD_LDS16(ag0, a0);  GLOAD_LDS16(ag1, a0 + 512);
    GLOAD_LDS16(bg0, b0);
    if constexpr (BN == 128) GLOAD_LDS16(bg1, b0 + 512);
  }
  int cur = 0;
  for (int t = 0; t < nk; ++t) {
    if (t + 1 < nk) {                            // issue tile t+1 (async)
      int k0 = (t + 1) << 5;
      u16* a0 = SM + (cur ^ 1) * 4096 + wave * 1024;
      u16* b0 = SM + ASZ + (cur ^ 1) * (BN * 32) + wave * (BN / 4) * 32;
      GLOAD_LDS16(ag0 + (size_t)(t + 1) * slab, a0);
      GLOAD_LDS16(ag1 + (size_t)(t + 1) * slab, a0 + 512);
      GLOAD_LDS16(bg0 + k0, b0);
      if constexpr (BN == 128) GLOAD_LDS16(bg1 + k0, b0 + 512);
      if constexpr (BN == 128) asm volatile("s_waitcnt vmcnt(4)" ::: "memory");
      else                     asm volatile("s_waitcnt vmcnt(3)" ::: "memory");
    } else {
      asm volatile("s_waitcnt vmcnt(0)" ::: "memory");
    }
    __builtin_amdgcn_s_barrier();                // ALL waves' tile t landed
    const u16* ar = SM + cur * 4096 + aoff;
    const u16* br = SM + ASZ + cur * (BN * 32) + boff;
    bf16x8 af[4], bf[FN];
    #pragma unroll
    for (int f = 0; f < 4; ++f)
      af[f] = *reinterpret_cast<const bf16x8*>(ar + f * 512);
    #pragma unroll
    for (int f = 0; f < FN; ++f)
      bf[f] = *reinterpret_cast<const bf16x8*>(br + f * 512);
    #pragma unroll
    for (int fm = 0; fm < 4; ++fm)
      #pragma unroll
      for (int fn = 0; fn < FN; ++fn)
        acc[fm][fn] = __builtin_amdgcn_mfma_f32_16x16x32_bf16(af[fm], bf[fn], acc[fm][fn], 0, 0, 0);
    asm volatile("s_waitcnt lgkmcnt(0)" ::: "memory");
    __builtin_amdgcn_s_barrier();                // reads done before overwrite
    cur ^= 1;
  }
  // ---- epilogue. D layout: col=lane&15, row=(lane>>4)*4+j ----
  if constexpr (MODE == 0 || MODE == 2) {
    u16* T = SM;                                 // 128*BN u16 <= ASZ+BSZ
    #pragma unroll
    for (int fm = 0; fm < 4; ++fm) {
      #pragma unroll
      for (int fn = 0; fn < FN; ++fn) {
        int cc = wc * (BN / 2) + fn * 16 + r16;
        float bsv = bias[bn0 + cc];
        #pragma unroll
        for (int j = 0; j < 4; ++j) {
          int rr = wr * 64 + fm * 16 + q4 * 4 + j;
          float v = acc[fm][fn][j] + bsv;
          if constexpr (MODE == 2)
            v = 0.5f * v * (1.0f + erff(v * 0.70710678118654752440f));
          T[rr * BN + cc] = f2b(v);
        }
      }
    }
    __syncthreads();                             // drains ds_writes + barrier
    constexpr int CPR = BN / 8;                  // 16B chunks per row
    u16* out = (u16*)outv;
    #pragma unroll
    for (int i = 0; i < 128 * CPR / 256; ++i) {
      int idx = i * 256 + tid;
      int row = idx / CPR, col8 = (idx - row * CPR) * 8;
      uint4 v = *reinterpret_cast<const uint4*>(T + row * BN + col8);
      int c = bn0 + col8;
      int r = bm0 + row;
      if constexpr (MODE == 0) {
        int s = c / DIMC; int rem = c - s * DIMC;
        int nh = rem / HDC; int ch = rem - nh * HDC;
        int b = r / 3136; int hw = r - b * 3136;
        *reinterpret_cast<uint4*>(
            out + (((size_t)(s * 64 + b * 8 + nh)) * 3136 + hw) * 48 + ch) = v;
      } else {
        *reinterpret_cast<uint4*>(
            out + (size_t)(c >> 5) * M * 32 + (size_t)r * 32 + (c & 31)) = v;
      }
    }
  } else {
    int c0 = bn0 + wc * (BN / 2) + r16;
    int r0 = bm0 + wr * 64 + q4 * 4;
    #pragma unroll
    for (int fm = 0; fm < 4; ++fm) {
      #pragma unroll
      for (int fn = 0; fn < FN; ++fn) {
        int c = c0 + fn * 16;
        float bsv = bias[c];
        #pragma unroll
        for (int j = 0; j < 4; ++j) {
          int r = r0 + fm * 16 + j;
          float v = acc[fm][fn][j] + bsv;
          float* out = (float*)outv;
          size_t idx = (size_t)r * N + c;
          out[idx] = v + res[idx];
        }
      }
    }
  }
}

// ---- depthwise 3x3 conv (pad 1) + LayerNorm over 48 channels ----
// k-branch (s==1) gamma/beta pre-scaled by 48^-0.5 * log2(e): folds both the
// QK^T scale AND the softmax exp->exp2 conversion into this LN.
__global__ __launch_bounds__(256)
void convln_kernel(const u16* __restrict__ qkv,
                   const float* __restrict__ wq, const float* __restrict__ wk, const float* __restrict__ wv,
                   const float* __restrict__ gq, const float* __restrict__ bq,
                   const float* __restrict__ gk, const float* __restrict__ bk,
                   const float* __restrict__ gv, const float* __restrict__ bv,
                   u16* __restrict__ out) {
  __shared__ __attribute__((aligned(16))) float wsm[432];
  __shared__ __attribute__((aligned(16))) float gsm[48];
  __shared__ __attribute__((aligned(16))) float bsm[48];
  int tid = threadIdx.x;
  int sb = blockIdx.y;                  // 0..191 = s*64 + bnh
  int s = sb >> 6;
  const float* wgt = (s == 0) ? wq : ((s == 1) ? wk : wv);
  const float* gam = (s == 0) ? gq : ((s == 1) ? gk : gv);
  const float* bet = (s == 0) ? bq : ((s == 1) ? bk : bv);
  float sc = (s == 1) ? SCALEF * LOG2E : 1.0f;
  for (int i = tid; i < 432; i += 256) wsm[i] = wgt[i];
  if (tid < 48) { gsm[tid] = gam[tid] * sc; bsm[tid] = bet[tid] * sc; }
  __syncthreads();
  int hw = blockIdx.x * 256 + tid;
  if (hw >= 3136) return;
  int h = hw / 56, w = hw - h * 56;
  const u16* img = qkv + (size_t)sb * (3136 * 48);
  float acc[48];
  #pragma unroll
  for (int c = 0; c < 48; ++c) acc[c] = 0.f;
  #pragma unroll
  for (int dy = -1; dy <= 1; ++dy) {
    int hh = h + dy;
    if ((unsigned)hh >= 56u) continue;
    #pragma unroll
    for (int dx = -1; dx <= 1; ++dx) {
      int ww = w + dx;
      if ((unsigned)ww >= 56u) continue;
      const uint4* p = reinterpret_cast<const uint4*>(img + (size_t)(hh * 56 + ww) * 48);
      const float4* wr = reinterpret_cast<const float4*>(wsm + ((dy + 1) * 3 + (dx + 1)) * 48);
      #pragma unroll
      for (int g = 0; g < 6; ++g) {
        uint4 v = p[g];
        float4 w0 = wr[g * 2], w1 = wr[g * 2 + 1];
        acc[g * 8 + 0] += uasf(v.x << 16)          * w0.x;
        acc[g * 8 + 1] += uasf(v.x & 0xFFFF0000u)  * w0.y;
        acc[g * 8 + 2] += uasf(v.y << 16)          * w0.z;
        acc[g * 8 + 3] += uasf(v.y & 0xFFFF0000u)  * w0.w;
        acc[g * 8 + 4] += uasf(v.z << 16)          * w1.x;
        acc[g * 8 + 5] += uasf(v.z & 0xFFFF0000u)  * w1.y;
        acc[g * 8 + 6] += uasf(v.w << 16)          * w1.z;
        acc[g * 8 + 7] += uasf(v.w & 0xFFFF0000u)  * w1.w;
      }
    }
  }
  float sum = 0.f, ssq = 0.f;
  #pragma unroll
  for (int c = 0; c < 48; ++c) { sum += acc[c]; ssq += acc[c] * acc[c]; }
  float mean = sum * (1.f / 48.f);
  float var = ssq * (1.f / 48.f) - mean * mean;
  float inv = rsqrtf(var + EPSF);
  u16* op = out + ((size_t)sb * 3136 + hw) * 48;
  #pragma unroll
  for (int g = 0; g < 6; ++g) {
    const float4 gm0 = *reinterpret_cast<const float4*>(gsm + g * 8);
    const float4 gm1 = *reinterpret_cast<const float4*>(gsm + g * 8 + 4);
    const float4 bt0 = *reinterpret_cast<const float4*>(bsm + g * 8);
    const float4 bt1 = *reinterpret_cast<const float4*>(bsm + g * 8 + 4);
    uint4 ov;
    u32 a0 = f2b((acc[g * 8 + 0] - mean) * inv * gm0.x + bt0.x);
    u32 a1 = f2b((acc[g * 8 + 1] - mean) * inv * gm0.y + bt0.y);
    u32 a2 = f2b((acc[g * 8 + 2] - mean) * inv * gm0.z + bt0.z);
    u32 a3 = f2b((acc[g * 8 + 3] - mean) * inv * gm0.w + bt0.w);
    u32 a4 = f2b((acc[g * 8 + 4] - mean) * inv * gm1.x + bt1.x);
    u32 a5 = f2b((acc[g * 8 + 5] - mean) * inv * gm1.y + bt1.y);
    u32 a6 = f2b((acc[g * 8 + 6] - mean) * inv * gm1.z + bt1.z);
    u32 a7 = f2b((acc[g * 8 + 7] - mean) * inv * gm1.w + bt1.w);
    ov.x = a0 | (a1 << 16);
    ov.y = a2 | (a3 << 16);
    ov.z = a4 | (a5 << 16);
    ov.w = a6 | (a7 << 16);
    *reinterpret_cast<uint4*>(op + g * 8) = ov;
  }
}

// ---- MFMA window attention, extended-K bias fold, log2-domain softmax ----
// Dual-fragment pipeline (T15 analog): waves 0-4 compute BOTH QK^T score sets
// before the first softmax so the scheduler can overlap frag2's MFMAs (matrix
// pipe) with frag1's softmax (VALU pipe). Per-wave only -- no barrier changes.
constexpr int LDP = 256;
constexpr int LDK = 104;
constexpr int LDV = 228;

#define QK_PHASE(MF, S)                                                        \
  {                                                                            \
    int qrow_ = (MF) * 16 + r16; int qc_ = qrow_ < 196 ? qrow_ : 195;          \
    int hq_ = wh * 14 + qc_ / 14, wq_ = wwn * 14 + qc_ % 14;                   \
    const u16* qpg_ = qkvc + qbase + (size_t)(hq_ * 56 + wq_) * 48;            \
    const u16* qe_ = QE + qrow_ * 56;                                          \
    bf16x8 af0_ = *reinterpret_cast<const bf16x8*>(qpg_ + q4 * 8);             \
    bf16x8 af1_;                                                               \
    if (q4 < 2) af1_ = *reinterpret_cast<const bf16x8*>(qpg_ + 32 + q4 * 8);   \
    else        af1_ = *reinterpret_cast<const bf16x8*>(qe_ + (q4 - 2) * 8);   \
    bf16x8 af2_ = *reinterpret_cast<const bf16x8*>(qe_ + 16 + q4 * 8);         \
    _Pragma("unroll")                                                          \
    for (int nf = 0; nf < 13; ++nf) {                                          \
      const u16* kr_ = KL + (nf * 16 + r16) * LDK;                             \
      bf16x8 b0_ = *reinterpret_cast<const bf16x8*>(kr_ + q4 * 8);             \
      bf16x8 b1_ = *reinterpret_cast<const bf16x8*>(kr_ + 32 + q4 * 8);        \
      bf16x8 b2_ = *reinterpret_cast<const bf16x8*>(kr_ + 64 + q4 * 8);        \
      f32x4 a_ = {};                                                           \
      a_ = MFMA16(af0_, b0_, a_);                                              \
      a_ = MFMA16(af1_, b1_, a_);                                              \
      a_ = MFMA16(af2_, b2_, a_);                                              \
      (S)[nf] = a_;                                                            \
    }                                                                          \
  }

#define SM_PV(MF, S)                                                           \
  {                                                                            \
    int rowb_ = (MF) * 16 + q4 * 4;                                            \
    float mrow_[4], den_[4];                                                   \
    _Pragma("unroll")                                                          \
    for (int j = 0; j < 4; ++j) {                                              \
      float mm_ = (S)[0][j];                                                   \
      _Pragma("unroll")                                                        \
      for (int nf = 1; nf < 13; ++nf) mm_ = fmaxf(mm_, (S)[nf][j]);            \
      _Pragma("unroll")                                                        \
      for (int off = 1; off < 16; off <<= 1) mm_ = fmaxf(mm_, __shfl_xor(mm_, off)); \
      mrow_[j] = mm_; den_[j] = 0.f;                                           \
    }                                                                          \
    _Pragma("unroll")                                                          \
    for (int nf = 0; nf < 13; ++nf) {                                          \
      _Pragma("unroll")                                                        \
      for (int j = 0; j < 4; ++j) {                                            \
        float p_ = __builtin_amdgcn_exp2f((S)[nf][j] - mrow_[j]);              \
        den_[j] += p_;                                                         \
        Pw[(q4 * 4 + j) * LDP + (((nf * 16 + r16) ^ (q4 << 4)))] = f2b(p_);    \
      }                                                                        \
    }                                                                          \
    _Pragma("unroll")                                                          \
    for (int j = 0; j < 4; ++j)                                                \
      _Pragma("unroll")                                                        \
      for (int off = 1; off < 16; off <<= 1) den_[j] += __shfl_xor(den_[j], off); \
    f32x4 o_[3] = {};                                                          \
    _Pragma("unroll")                                                          \
    for (int ks = 0; ks < 7; ++ks) {                                           \
      bf16x8 ap_ = *reinterpret_cast<const bf16x8*>(                           \
          Pw + r16 * LDP + ((ks * 32 + q4 * 8) ^ (((r16 >> 2) & 3) << 4)));    \
      _Pragma("unroll")                                                        \
      for (int nf3 = 0; nf3 < 3; ++nf3) {                                      \
        bf16x8 bv_ = *reinterpret_cast<const bf16x8*>(                         \
            VT + (nf3 * 16 + r16) * LDV + ks * 32 + q4 * 8);                   \
        o_[nf3] = MFMA16(ap_, bv_, o_[nf3]);                                   \
      }                                                                        \
    }                                                                          \
    _Pragma("unroll")                                                          \
    for (int j = 0; j < 4; ++j) {                                              \
      int row_ = rowb_ + j;                                                    \
      if (row_ < 196) {                                                        \
        float rden_ = 1.f / den_[j];                                           \
        int rh_ = row_ / 14;                                                   \
        int h_ = wh * 14 + rh_, w_ = wwn * 14 + row_ - rh_ * 14;               \
        int tok_ = (bI * 56 + h_) * 56 + w_;                                   \
        const u16* qg_ = qkvc + qbase + (size_t)(h_ * 56 + w_) * 48;           \
        _Pragma("unroll")                                                      \
        for (int nf3 = 0; nf3 < 3; ++nf3) {                                    \
          int col_ = nf3 * 16 + r16;                                           \
          int cg_ = nhI * 48 + col_;                                           \
          obuf[(size_t)(cg_ >> 5) * (NTOK * 32) + (size_t)tok_ * 32 + (cg_ & 31)] = \
              f2b(o_[nf3][j] * rden_ + b2f(qg_[col_]));                        \
        }                                                                      \
      }                                                                        \
    }                                                                          \
  }

__global__ __launch_bounds__(512, 1)
void attn_kernel(const u16* __restrict__ qkvc, const float* __restrict__ rel_h,
                 const float* __restrict__ rel_w, u16* __restrict__ obuf) {
  __shared__ __attribute__((aligned(16))) u16 KL[208 * LDK];
  __shared__ __attribute__((aligned(16))) u16 VT[48 * LDV];
  __shared__ __attribute__((aligned(16))) u16 QE[208 * 56];
  __shared__ __attribute__((aligned(16))) u16 PB[8 * 16 * LDP];

  int wid = blockIdx.x;
  int bnh = wid >> 4, wrem = wid & 15, wh = wrem >> 2, wwn = wrem & 3;
  int tid = threadIdx.x;
  int wave = tid >> 6, lane = tid & 63;
  int q4 = lane >> 4, r16 = lane & 15;

  { u32* z;
    z = (u32*)KL; for (int i = tid; i < 208 * LDK / 2; i += 512) z[i] = 0;
    z = (u32*)VT; for (int i = tid; i < 48 * LDV / 2; i += 512) z[i] = 0;
    // QRW B-operand reads PB rows 0..63 x cols 0..63 (stride 72); LDS start
    // state undefined; 0*NaN=NaN -> must zero the region.
    z = (u32*)PB; for (int i = tid; i < 64 * 72 / 2; i += 512) z[i] = 0;
  }
  __syncthreads();
  size_t qbase = (size_t)bnh * 3136 * 48;
  size_t kbase = ((size_t)(64 + bnh) * 3136) * 48;
  size_t vbase = ((size_t)(128 + bnh) * 3136) * 48;
  for (int i = tid; i < 196 * 12; i += 512) {
    int r = i / 12, c4 = (i - r * 12) * 4;
    int h = wh * 14 + r / 14, w = wwn * 14 + r % 14;
    size_t g = (size_t)(h * 56 + w) * 48 + c4;
    ushort4 kv = *reinterpret_cast<const ushort4*>(qkvc + kbase + g);
    *reinterpret_cast<ushort4*>(KL + r * LDK + c4) = kv;   // pre-scaled k
    ushort4 vv = *reinterpret_cast<const ushort4*>(qkvc + vbase + g);
    VT[(c4 + 0) * LDV + r] = vv.x; VT[(c4 + 1) * LDV + r] = vv.y;
    VT[(c4 + 2) * LDV + r] = vv.z; VT[(c4 + 3) * LDV + r] = vv.w;
  }
  // K one-hot / mask flag columns (bf16 1.0 = 0x3F80)
  for (int r = tid; r < 208; r += 512) {
    if (r < 196) {
      KL[r * LDK + 48 + r / 14] = 0x3F80;
      KL[r * LDK + 62 + r % 14] = 0x3F80;
    } else {
      KL[r * LDK + 76] = 0x3F80;
    }
  }
  // Rel staged *log2e so QE bias tables are in log2 domain
  for (int i = tid; i < 54 * 48; i += 512) {
    int r = i / 48, c = i - r * 48;
    float v = (r < 27) ? rel_h[r * 48 + c] : rel_w[(r - 27) * 48 + c];
    PB[r * 72 + c] = f2b(v * LOG2E);
  }
  __syncthreads();
  // QE = Q @ Rel^T
  for (int mf = wave; mf < 13; mf += 8) {
    int qrow = mf * 16 + r16; int qc = qrow < 196 ? qrow : 195;
    int hq = wh * 14 + qc / 14, wq = wwn * 14 + qc % 14;
    const u16* qpg = qkvc + qbase + (size_t)(hq * 56 + wq) * 48;
    bf16x8 af0 = *reinterpret_cast<const bf16x8*>(qpg + q4 * 8);
    bf16x8 af1 = {0, 0, 0, 0, 0, 0, 0, 0};
    if (q4 < 2) af1 = *reinterpret_cast<const bf16x8*>(qpg + 32 + q4 * 8);
    #pragma unroll
    for (int nf = 0; nf < 4; ++nf) {
      bf16x8 b0 = *reinterpret_cast<const bf16x8*>(PB + (nf * 16 + r16) * 72 + q4 * 8);
      bf16x8 b1 = *reinterpret_cast<const bf16x8*>(PB + (nf * 16 + r16) * 72 + 32 + q4 * 8);
      f32x4 acc = {};
      acc = MFMA16(af0, b0, acc);
      acc = MFMA16(af1, b1, acc);
      int col = nf * 16 + r16;
      if (col < 54) {
        #pragma unroll
        for (int j = 0; j < 4; ++j)
          QE[(mf * 16 + q4 * 4 + j) * 56 + col] = f2b(acc[j]);
      }
    }
  }
  __syncthreads();
  u16 bhv[14], bwv[14];
  {
    int t = tid;
    if (t < 208) {
      int qc = t < 196 ? t : 195;
      int qh = qc / 14, qw = qc - qh * 14;
      const u16* src = QE + t * 56;
      #pragma unroll
      for (int z = 0; z < 14; ++z) {
        bhv[z] = src[qh + 13 - z];
        bwv[z] = src[27 + qw + 13 - z];
      }
    }
  }
  __syncthreads();
  {
    int t = tid;
    if (t < 208) {
      u16* dst = QE + t * 56;
      #pragma unroll
      for (int z = 0; z < 14; ++z) { dst[z] = bhv[z]; dst[14 + z] = bwv[z]; }
      dst[28] = f2b(-30000.0f);
      #pragma unroll
      for (int z = 29; z < 56; ++z) dst[z] = 0;
    }
  }
  // zero this wave's P-tile pad slots (swizzled positions, XOR q4<<4 scheme)
  u16* Pw = PB + wave * 16 * LDP;
  for (int i = lane; i < 16 * 16; i += 64) {
    int r = i >> 4;
    Pw[r * LDP + ((208 + (i & 15)) ^ (((r >> 2) & 3) << 4))] = 0;
  }
  __syncthreads();
  int bI = bnh >> 3, nhI = bnh & 7;
  // ---- dual-fragment main: QK1, QK2 issued before SM1 (pipe overlap) ----
  {
    f32x4 s0[13];
    QK_PHASE(wave, s0);
    if (wave + 8 < 13) {
      f32x4 s1[13];
      QK_PHASE(wave + 8, s1);
      SM_PV(wave, s0);
      SM_PV(wave + 8, s1);
    } else {
      SM_PV(wave, s0);
    }
  }
}

extern "C" void kernel_launch(void* const* d_in, const int* in_sizes, int n_in,
                              void* d_out, int out_size, void* d_ws, size_t ws_size,
                              hipStream_t stream) {
  const float* x1      = (const float*)d_in[0];
  const float* x2      = (const float*)d_in[1];
  const float* norm1_w = (const float*)d_in[2];
  const float* norm1_b = (const float*)d_in[3];
  const float* qkv_w   = (const float*)d_in[4];
  const float* qkv_b   = (const float*)d_in[5];
  const float* poolq_w = (const float*)d_in[6];
  const float* poolk_w = (const float*)d_in[7];
  const float* poolv_w = (const float*)d_in[8];
  const float* nq_w    = (const float*)d_in[9];
  const float* nq_b    = (const float*)d_in[10];
  const float* nk_w    = (const float*)d_in[11];
  const float* nk_b    = (const float*)d_in[12];
  const float* nv_w    = (const float*)d_in[13];
  const float* nv_b    = (const float*)d_in[14];
  const float* rel_h   = (const float*)d_in[15];
  const float* rel_w   = (const float*)d_in[16];
  const float* proj_w  = (const float*)d_in[17];
  const float* proj_b  = (const float*)d_in[18];
  const float* norm2_w = (const float*)d_in[19];
  const float* norm2_b = (const float*)d_in[20];
  const float* fc1_w   = (const float*)d_in[21];
  const float* fc1_b   = (const float*)d_in[22];
  const float* fc2_w   = (const float*)d_in[23];
  const float* fc2_b   = (const float*)d_in[24];

  // ws overlay (u16 units). Peak = 57,802,752 u16 = 115.6 MB
  u16* ws      = (u16*)d_ws;
  u16* qkv     = ws;                  // [0, 28901376)   qkv bf16, [3,64,3136,48]
  u16* xn      = ws + 28901376;       // LN(x1) bf16, K-blocked [12][25088][32]
  u16* qkvc    = ws + 28901376;       // post conv+LN (after xn dead)
  u16* obuf    = ws;                  // attn out bf16 K-blocked [12][25088][32]
  u16* h1      = ws;                  // gelu(fc1) bf16 K-blocked [48][25088][32]
  u16* yn      = ws + 48168960;       // LN(y1) bf16 K-blocked [12][25088][32]
  u16* qkv_wt  = ws + 38535168;       // bf16 [1152][384] (dies at step 3)
  u16* proj_wt = ws + 9633792;        // bf16 [384][384]  (after qkv dead)
  u16* fc1_wt  = ws + 38535168;       // bf16 [1536][384] (after qkvc dead)
  u16* fc2_wt  = ws + 39124992;       // bf16 [384][1536]
  float* y1 = (float*)d_out;          // 9633792 f32
  float* y2 = y1 + 9633792;

  // 0a. convert qkv weights (transposed [N][K] bf16)
  wcvt_kernel<<<dim3(12, 36), 256, 0, stream>>>(qkv_w, qkv_wt, 384, 1152);
  // 1. xn = LN(x1)  (K-blocked out)
  ln384_kernel<<<NTOK / 4, 256, 0, stream>>>(x1, norm1_w, norm1_b, xn);
  // 2. qkv = xn @ qkv_w + qkv_b  (MFMA, scattered layout; XCD-chunked grid)
  mgemm_kernel<0, 128><<<196 * 9, 256, 0, stream>>>(xn, qkv_wt, qkv_b, nullptr, qkv, NTOK, 1152, 384);
  // 3. q/k/v = LN(dwconv3x3(qkv))  (k pre-scaled by 48^-0.5 * log2e)
  convln_kernel<<<dim3(13, 192), 256, 0, stream>>>(qkv, poolq_w, poolk_w, poolv_w,
                                                   nq_w, nq_b, nk_w, nk_b, nv_w, nv_b, qkvc);
  // 0b. convert proj weights (qkv region now dead)
  wcvt_kernel<<<dim3(12, 12), 256, 0, stream>>>(proj_w, proj_wt, 384, 384);
  // 4. MFMA window attention (+ ori_q residual), K-blocked obuf
  attn_kernel<<<1024, 512, 0, stream>>>(qkvc, rel_h, rel_w, obuf);
  // 0c. convert mlp weights (qkvc region now dead)
  wcvt_kernel<<<dim3(12, 48), 256, 0, stream>>>(fc1_w, fc1_wt, 384, 1536);
  wcvt_kernel<<<dim3(48, 12), 256, 0, stream>>>(fc2_w, fc2_wt, 1536, 384);
  // 5. y1 = x1 + obuf @ proj_w + proj_b  (skinny-N -> BN=64; XCD-chunked)
  mgemm_kernel<1, 64><<<196 * 6, 256, 0, stream>>>(obuf, proj_wt, proj_b, x1, y1, NTOK, 384, 384);
  // 6. yn = LN(y1)  (K-blocked out)
  ln384_kernel<<<NTOK / 4, 256, 0, stream>>>(y1, norm2_w, norm2_b, yn);
  // 7. h1 = gelu(yn @ fc1_w + fc1_b)  (K-blocked out; XCD-chunked)
  mgemm_kernel<2, 128><<<196 * 12, 256, 0, stream>>>(yn, fc1_wt, fc1_b, nullptr, h1, NTOK, 1536, 384);
  // 8. y2 = x2 + h1 @ fc2_w + fc2_b  (skinny-N -> BN=64; XCD-chunked)
  mgemm_kernel<1, 64><<<196 * 6, 256, 0, stream>>>(h1, fc2_wt, fc2_b, x2, y2, NTOK, 384, 1536);
}

// Round 23
// 319.296 us; speedup vs baseline: 1.0380x; 1.0380x over previous
//
#include <hip/hip_runtime.h>
#include <hip/hip_bf16.h>

typedef unsigned short u16;
typedef unsigned int u32;

#define DEVI __device__ __forceinline__

constexpr int BB = 8, HHc = 56, WWc = 56, DIMC = 384, NHC = 8, HDC = 48, WSZ = 14;
constexpr int NTOK = BB * HHc * WWc;          // 25088
constexpr int HIDC = 4 * DIMC;                // 1536
constexpr float EPSF = 1e-5f;
constexpr float SCALEF = 0.14433756729740643f;   // 48^-0.5
constexpr float LOG2E = 1.4426950408889634f;

typedef short bf16x8 __attribute__((ext_vector_type(8)));
typedef float f32x4 __attribute__((ext_vector_type(4)));

// ---- bf16 helpers (raw ushort view) ----
DEVI float b2f(u16 u) { u32 x = ((u32)u) << 16; float f; __builtin_memcpy(&f, &x, 4); return f; }
DEVI float uasf(u32 x) { float f; __builtin_memcpy(&f, &x, 4); return f; }
DEVI u16 f2b(float f) {
  u32 x; __builtin_memcpy(&x, &f, 4);
  u32 r = (x >> 16) & 1u; x += 0x7fffu + r;
  return (u16)(x >> 16);
}

DEVI float wred_sum(float v) {
  #pragma unroll
  for (int o = 32; o; o >>= 1) v += __shfl_xor(v, o);
  return v;
}

// async global->LDS, 16B per lane; dest = uniform base + lane*16
#define GLOAD_LDS16(g, l) __builtin_amdgcn_global_load_lds( \
    (const __attribute__((address_space(1))) u32*)(g), \
    (__attribute__((address_space(3))) u32*)(l), 16, 0, 0)

#define MFMA16(a, b, c) __builtin_amdgcn_mfma_f32_16x16x32_bf16((a), (b), (c), 0, 0, 0)

// ---- weight convert f32 [K][N] -> bf16 [N][K], LDS-tiled transpose ----
__global__ __launch_bounds__(256)
void wcvt_kernel(const float* __restrict__ in, u16* __restrict__ out, int K, int N) {
  __shared__ float t[32][33];
  int bk = blockIdx.x * 32, bn = blockIdx.y * 32;
  int tx = threadIdx.x & 31, ty = threadIdx.x >> 5;
  #pragma unroll
  for (int i = 0; i < 32; i += 8)
    t[ty + i][tx] = in[(size_t)(bk + ty + i) * N + bn + tx];
  __syncthreads();
  #pragma unroll
  for (int i = 0; i < 32; i += 8)
    out[(size_t)(bn + ty + i) * K + bk + tx] = f2b(t[tx][ty + i]);
}

// ---- LayerNorm over 384: f32 in -> bf16 out, K-BLOCKED [12][NTOK][32] ----
__global__ __launch_bounds__(256)
void ln384_kernel(const float* __restrict__ x, const float* __restrict__ w,
                  const float* __restrict__ b, u16* __restrict__ out) {
  int wave = threadIdx.x >> 6, lane = threadIdx.x & 63;
  int tok = blockIdx.x * 4 + wave;
  if (tok >= NTOK) return;
  const float* xr = x + (size_t)tok * DIMC;
  float v[6]; float s = 0.f, ss = 0.f;
  #pragma unroll
  for (int i = 0; i < 6; ++i) {
    v[i] = xr[lane + i * 64];
    s += v[i]; ss += v[i] * v[i];
  }
  s = wred_sum(s); ss = wred_sum(ss);
  float mean = s * (1.f / 384.f);
  float var = ss * (1.f / 384.f) - mean * mean;
  float inv = rsqrtf(var + EPSF);
  #pragma unroll
  for (int i = 0; i < 6; ++i) {
    int c = lane + i * 64;
    out[(size_t)(c >> 5) * (NTOK * 32) + (size_t)tok * 32 + (c & 31)] =
        f2b((v[i] - mean) * inv * w[c] + b[c]);
  }
}

// ---- MFMA GEMM: C[M,N] = A(bf16, K-BLOCKED [K/32][M][32]) @ Wt^T + bias ----
// 128xBN tile, BK=32, 4 waves; 2-buffer LDS, TWO barriers per k-step
// (STAGE -> vmcnt(counted) -> barrier publishes all waves' loads;
//  reads+MFMA -> lgkm(0) -> barrier protects buffer overwrite).
// vmcnt is PER-WAVE: barrier must come AFTER the vmcnt (r18 race lesson).
// Flat grid, col-fastest + chunked XCD swizzle; MODE 0/2 bf16 out via
// LDS-staged coalesced epilogue.
template<int MODE, int BN>
__global__ __launch_bounds__(256)
void mgemm_kernel(const u16* __restrict__ A, const u16* __restrict__ Wt,
                  const float* __restrict__ bias, const float* __restrict__ res,
                  void* __restrict__ outv, int M, int N, int K) {
  constexpr int FN = BN / 32;                    // col frags per wave (4 or 2)
  constexpr int ASZ = 2 * 128 * 32;              // u16; 2 A buffers
  constexpr int BSZ = 2 * BN * 32;               // u16; 2 B buffers
  __shared__ __attribute__((aligned(16))) u16 SM[ASZ + BSZ];
  // ---- chunked XCD swizzle ----
  int nblk = gridDim.x;
  int qch = nblk >> 3, rch = nblk & 7;
  int orig = blockIdx.x;
  int xcd = orig & 7, off = orig >> 3;
  int tile = ((xcd < rch) ? xcd * (qch + 1) : rch * (qch + 1) + (xcd - rch) * qch) + off;
  int ncol = N / BN;
  int brow = tile / ncol, bcol = tile - brow * ncol;   // col-fastest
  int bm0 = brow * 128, bn0 = bcol * BN;
  int tid = threadIdx.x;
  int wave = tid >> 6, lane = tid & 63;
  int wr = wave >> 1, wc = wave & 1;
  int lrow = lane >> 2;
  int slot = (lane & 3) ^ ((lane >> 3) & 3);
  const size_t slab = (size_t)M * 32;            // one k-slab of A
  const u16* ag0 = A + (size_t)(bm0 + wave * 32 + lrow) * 32 + slot * 8;
  const u16* ag1 = ag0 + 16 * 32;
  const u16* bg0 = Wt + (size_t)(bn0 + wave * (BN / 4) + lrow) * K + slot * 8;
  const u16* bg1 = bg0 + (size_t)16 * K;         // used only when BN==128
  int q4 = lane >> 4, r16 = lane & 15;
  int rslot = (q4 ^ ((r16 >> 1) & 3)) * 8;       // de-swizzle on read
  int aoff = (wr * 64 + r16) * 32 + rslot;
  int boff = (wc * (BN / 2) + r16) * 32 + rslot;
  f32x4 acc[4][FN] = {};
  int nk = K >> 5;
  {  // prologue: stage tile 0 into buf 0
    u16* a0 = SM + wave * 1024;
    u16* b0 = SM + ASZ + wave * (BN / 4) * 32;
    GLOAD_LDS16(ag0, a0);  GLOAD_LDS16(ag1, a0 + 512);
    GLOAD_LDS16(bg0, b0);
    if constexpr (BN == 128) GLOAD_LDS16(bg1, b0 + 512);
  }
  int cur = 0;
  for (int t = 0; t < nk; ++t) {
    if (t + 1 < nk) {                            // issue tile t+1 (async)
      int k0 = (t + 1) << 5;
      u16* a0 = SM + (cur ^ 1) * 4096 + wave * 1024;
      u16* b0 = SM + ASZ + (cur ^ 1) * (BN * 32) + wave * (BN / 4) * 32;
      GLOAD_LDS16(ag0 + (size_t)(t + 1) * slab, a0);
      GLOAD_LDS16(ag1 + (size_t)(t + 1) * slab, a0 + 512);
      GLOAD_LDS16(bg0 + k0, b0);
      if constexpr (BN == 128) GLOAD_LDS16(bg1 + k0, b0 + 512);
      if constexpr (BN == 128) asm volatile("s_waitcnt vmcnt(4)" ::: "memory");
      else                     asm volatile("s_waitcnt vmcnt(3)" ::: "memory");
    } else {
      asm volatile("s_waitcnt vmcnt(0)" ::: "memory");
    }
    __builtin_amdgcn_s_barrier();                // ALL waves' tile t landed
    const u16* ar = SM + cur * 4096 + aoff;
    const u16* br = SM + ASZ + cur * (BN * 32) + boff;
    bf16x8 af[4], bf[FN];
    #pragma unroll
    for (int f = 0; f < 4; ++f)
      af[f] = *reinterpret_cast<const bf16x8*>(ar + f * 512);
    #pragma unroll
    for (int f = 0; f < FN; ++f)
      bf[f] = *reinterpret_cast<const bf16x8*>(br + f * 512);
    #pragma unroll
    for (int fm = 0; fm < 4; ++fm)
      #pragma unroll
      for (int fn = 0; fn < FN; ++fn)
        acc[fm][fn] = __builtin_amdgcn_mfma_f32_16x16x32_bf16(af[fm], bf[fn], acc[fm][fn], 0, 0, 0);
    asm volatile("s_waitcnt lgkmcnt(0)" ::: "memory");
    __builtin_amdgcn_s_barrier();                // reads done before overwrite
    cur ^= 1;
  }
  // ---- epilogue. D layout: col=lane&15, row=(lane>>4)*4+j ----
  if constexpr (MODE == 0 || MODE == 2) {
    u16* T = SM;                                 // 128*BN u16 <= ASZ+BSZ
    #pragma unroll
    for (int fm = 0; fm < 4; ++fm) {
      #pragma unroll
      for (int fn = 0; fn < FN; ++fn) {
        int cc = wc * (BN / 2) + fn * 16 + r16;
        float bsv = bias[bn0 + cc];
        #pragma unroll
        for (int j = 0; j < 4; ++j) {
          int rr = wr * 64 + fm * 16 + q4 * 4 + j;
          float v = acc[fm][fn][j] + bsv;
          if constexpr (MODE == 2)
            v = 0.5f * v * (1.0f + erff(v * 0.70710678118654752440f));
          T[rr * BN + cc] = f2b(v);
        }
      }
    }
    __syncthreads();                             // drains ds_writes + barrier
    constexpr int CPR = BN / 8;                  // 16B chunks per row
    u16* out = (u16*)outv;
    #pragma unroll
    for (int i = 0; i < 128 * CPR / 256; ++i) {
      int idx = i * 256 + tid;
      int row = idx / CPR, col8 = (idx - row * CPR) * 8;
      uint4 v = *reinterpret_cast<const uint4*>(T + row * BN + col8);
      int c = bn0 + col8;
      int r = bm0 + row;
      if constexpr (MODE == 0) {
        int s = c / DIMC; int rem = c - s * DIMC;
        int nh = rem / HDC; int ch = rem - nh * HDC;
        int b = r / 3136; int hw = r - b * 3136;
        *reinterpret_cast<uint4*>(
            out + (((size_t)(s * 64 + b * 8 + nh)) * 3136 + hw) * 48 + ch) = v;
      } else {
        *reinterpret_cast<uint4*>(
            out + (size_t)(c >> 5) * M * 32 + (size_t)r * 32 + (c & 31)) = v;
      }
    }
  } else {
    int c0 = bn0 + wc * (BN / 2) + r16;
    int r0 = bm0 + wr * 64 + q4 * 4;
    #pragma unroll
    for (int fm = 0; fm < 4; ++fm) {
      #pragma unroll
      for (int fn = 0; fn < FN; ++fn) {
        int c = c0 + fn * 16;
        float bsv = bias[c];
        #pragma unroll
        for (int j = 0; j < 4; ++j) {
          int r = r0 + fm * 16 + j;
          float v = acc[fm][fn][j] + bsv;
          float* out = (float*)outv;
          size_t idx = (size_t)r * N + c;
          out[idx] = v + res[idx];
        }
      }
    }
  }
}

// ---- depthwise 3x3 conv (pad 1) + LayerNorm over 48 channels ----
// k-branch (s==1) gamma/beta pre-scaled by 48^-0.5 * log2(e): folds both the
// QK^T scale AND the softmax exp->exp2 conversion into this LN.
__global__ __launch_bounds__(256)
void convln_kernel(const u16* __restrict__ qkv,
                   const float* __restrict__ wq, const float* __restrict__ wk, const float* __restrict__ wv,
                   const float* __restrict__ gq, const float* __restrict__ bq,
                   const float* __restrict__ gk, const float* __restrict__ bk,
                   const float* __restrict__ gv, const float* __restrict__ bv,
                   u16* __restrict__ out) {
  __shared__ __attribute__((aligned(16))) float wsm[432];
  __shared__ __attribute__((aligned(16))) float gsm[48];
  __shared__ __attribute__((aligned(16))) float bsm[48];
  int tid = threadIdx.x;
  int sb = blockIdx.y;                  // 0..191 = s*64 + bnh
  int s = sb >> 6;
  const float* wgt = (s == 0) ? wq : ((s == 1) ? wk : wv);
  const float* gam = (s == 0) ? gq : ((s == 1) ? gk : gv);
  const float* bet = (s == 0) ? bq : ((s == 1) ? bk : bv);
  float sc = (s == 1) ? SCALEF * LOG2E : 1.0f;
  for (int i = tid; i < 432; i += 256) wsm[i] = wgt[i];
  if (tid < 48) { gsm[tid] = gam[tid] * sc; bsm[tid] = bet[tid] * sc; }
  __syncthreads();
  int hw = blockIdx.x * 256 + tid;
  if (hw >= 3136) return;
  int h = hw / 56, w = hw - h * 56;
  const u16* img = qkv + (size_t)sb * (3136 * 48);
  float acc[48];
  #pragma unroll
  for (int c = 0; c < 48; ++c) acc[c] = 0.f;
  #pragma unroll
  for (int dy = -1; dy <= 1; ++dy) {
    int hh = h + dy;
    if ((unsigned)hh >= 56u) continue;
    #pragma unroll
    for (int dx = -1; dx <= 1; ++dx) {
      int ww = w + dx;
      if ((unsigned)ww >= 56u) continue;
      const uint4* p = reinterpret_cast<const uint4*>(img + (size_t)(hh * 56 + ww) * 48);
      const float4* wr = reinterpret_cast<const float4*>(wsm + ((dy + 1) * 3 + (dx + 1)) * 48);
      #pragma unroll
      for (int g = 0; g < 6; ++g) {
        uint4 v = p[g];
        float4 w0 = wr[g * 2], w1 = wr[g * 2 + 1];
        acc[g * 8 + 0] += uasf(v.x << 16)          * w0.x;
        acc[g * 8 + 1] += uasf(v.x & 0xFFFF0000u)  * w0.y;
        acc[g * 8 + 2] += uasf(v.y << 16)          * w0.z;
        acc[g * 8 + 3] += uasf(v.y & 0xFFFF0000u)  * w0.w;
        acc[g * 8 + 4] += uasf(v.z << 16)          * w1.x;
        acc[g * 8 + 5] += uasf(v.z & 0xFFFF0000u)  * w1.y;
        acc[g * 8 + 6] += uasf(v.w << 16)          * w1.z;
        acc[g * 8 + 7] += uasf(v.w & 0xFFFF0000u)  * w1.w;
      }
    }
  }
  float sum = 0.f, ssq = 0.f;
  #pragma unroll
  for (int c = 0; c < 48; ++c) { sum += acc[c]; ssq += acc[c] * acc[c]; }
  float mean = sum * (1.f / 48.f);
  float var = ssq * (1.f / 48.f) - mean * mean;
  float inv = rsqrtf(var + EPSF);
  u16* op = out + ((size_t)sb * 3136 + hw) * 48;
  #pragma unroll
  for (int g = 0; g < 6; ++g) {
    const float4 gm0 = *reinterpret_cast<const float4*>(gsm + g * 8);
    const float4 gm1 = *reinterpret_cast<const float4*>(gsm + g * 8 + 4);
    const float4 bt0 = *reinterpret_cast<const float4*>(bsm + g * 8);
    const float4 bt1 = *reinterpret_cast<const float4*>(bsm + g * 8 + 4);
    uint4 ov;
    u32 a0 = f2b((acc[g * 8 + 0] - mean) * inv * gm0.x + bt0.x);
    u32 a1 = f2b((acc[g * 8 + 1] - mean) * inv * gm0.y + bt0.y);
    u32 a2 = f2b((acc[g * 8 + 2] - mean) * inv * gm0.z + bt0.z);
    u32 a3 = f2b((acc[g * 8 + 3] - mean) * inv * gm0.w + bt0.w);
    u32 a4 = f2b((acc[g * 8 + 4] - mean) * inv * gm1.x + bt1.x);
    u32 a5 = f2b((acc[g * 8 + 5] - mean) * inv * gm1.y + bt1.y);
    u32 a6 = f2b((acc[g * 8 + 6] - mean) * inv * gm1.z + bt1.z);
    u32 a7 = f2b((acc[g * 8 + 7] - mean) * inv * gm1.w + bt1.w);
    ov.x = a0 | (a1 << 16);
    ov.y = a2 | (a3 << 16);
    ov.z = a4 | (a5 << 16);
    ov.w = a6 | (a7 << 16);
    *reinterpret_cast<uint4*>(op + g * 8) = ov;
  }
}

// ---- MFMA window attention, extended-K bias fold, log2-domain softmax ----
// Scores arrive as log2e * s_orig (k and Rel pre-scaled); p computed via the
// RAW v_exp_f32 (__builtin_amdgcn_exp2f) -- exp2f() is the slow precise OCML
// path (r20 lesson). P tiles: LDP=256 + XOR(q4<<4).
constexpr int LDP = 256;
constexpr int LDK = 104;
constexpr int LDV = 228;
__global__ __launch_bounds__(512, 1)
void attn_kernel(const u16* __restrict__ qkvc, const float* __restrict__ rel_h,
                 const float* __restrict__ rel_w, u16* __restrict__ obuf) {
  __shared__ __attribute__((aligned(16))) u16 KL[208 * LDK];
  __shared__ __attribute__((aligned(16))) u16 VT[48 * LDV];
  __shared__ __attribute__((aligned(16))) u16 QE[208 * 56];
  __shared__ __attribute__((aligned(16))) u16 PB[8 * 16 * LDP];

  int wid = blockIdx.x;
  int bnh = wid >> 4, wrem = wid & 15, wh = wrem >> 2, wwn = wrem & 3;
  int tid = threadIdx.x;
  int wave = tid >> 6, lane = tid & 63;
  int q4 = lane >> 4, r16 = lane & 15;

  { u32* z;
    z = (u32*)KL; for (int i = tid; i < 208 * LDK / 2; i += 512) z[i] = 0;
    z = (u32*)VT; for (int i = tid; i < 48 * LDV / 2; i += 512) z[i] = 0;
    // QRW B-operand reads PB rows 0..63 x cols 0..63 (stride 72); LDS start
    // state undefined; 0*NaN=NaN -> must zero the region.
    z = (u32*)PB; for (int i = tid; i < 64 * 72 / 2; i += 512) z[i] = 0;
  }
  __syncthreads();
  size_t qbase = (size_t)bnh * 3136 * 48;
  size_t kbase = ((size_t)(64 + bnh) * 3136) * 48;
  size_t vbase = ((size_t)(128 + bnh) * 3136) * 48;
  for (int i = tid; i < 196 * 12; i += 512) {
    int r = i / 12, c4 = (i - r * 12) * 4;
    int h = wh * 14 + r / 14, w = wwn * 14 + r % 14;
    size_t g = (size_t)(h * 56 + w) * 48 + c4;
    ushort4 kv = *reinterpret_cast<const ushort4*>(qkvc + kbase + g);
    *reinterpret_cast<ushort4*>(KL + r * LDK + c4) = kv;   // pre-scaled k
    ushort4 vv = *reinterpret_cast<const ushort4*>(qkvc + vbase + g);
    VT[(c4 + 0) * LDV + r] = vv.x; VT[(c4 + 1) * LDV + r] = vv.y;
    VT[(c4 + 2) * LDV + r] = vv.z; VT[(c4 + 3) * LDV + r] = vv.w;
  }
  // K one-hot / mask flag columns (bf16 1.0 = 0x3F80)
  for (int r = tid; r < 208; r += 512) {
    if (r < 196) {
      KL[r * LDK + 48 + r / 14] = 0x3F80;
      KL[r * LDK + 62 + r % 14] = 0x3F80;
    } else {
      KL[r * LDK + 76] = 0x3F80;
    }
  }
  // Rel staged *log2e so QE bias tables are in log2 domain
  for (int i = tid; i < 54 * 48; i += 512) {
    int r = i / 48, c = i - r * 48;
    float v = (r < 27) ? rel_h[r * 48 + c] : rel_w[(r - 27) * 48 + c];
    PB[r * 72 + c] = f2b(v * LOG2E);
  }
  __syncthreads();
  // QE = Q @ Rel^T
  for (int mf = wave; mf < 13; mf += 8) {
    int qrow = mf * 16 + r16; int qc = qrow < 196 ? qrow : 195;
    int hq = wh * 14 + qc / 14, wq = wwn * 14 + qc % 14;
    const u16* qpg = qkvc + qbase + (size_t)(hq * 56 + wq) * 48;
    bf16x8 af0 = *reinterpret_cast<const bf16x8*>(qpg + q4 * 8);
    bf16x8 af1 = {0, 0, 0, 0, 0, 0, 0, 0};
    if (q4 < 2) af1 = *reinterpret_cast<const bf16x8*>(qpg + 32 + q4 * 8);
    #pragma unroll
    for (int nf = 0; nf < 4; ++nf) {
      bf16x8 b0 = *reinterpret_cast<const bf16x8*>(PB + (nf * 16 + r16) * 72 + q4 * 8);
      bf16x8 b1 = *reinterpret_cast<const bf16x8*>(PB + (nf * 16 + r16) * 72 + 32 + q4 * 8);
      f32x4 acc = {};
      acc = MFMA16(af0, b0, acc);
      acc = MFMA16(af1, b1, acc);
      int col = nf * 16 + r16;
      if (col < 54) {
        #pragma unroll
        for (int j = 0; j < 4; ++j)
          QE[(mf * 16 + q4 * 4 + j) * 56 + col] = f2b(acc[j]);
      }
    }
  }
  __syncthreads();
  u16 bhv[14], bwv[14];
  {
    int t = tid;
    if (t < 208) {
      int qc = t < 196 ? t : 195;
      int qh = qc / 14, qw = qc - qh * 14;
      const u16* src = QE + t * 56;
      #pragma unroll
      for (int z = 0; z < 14; ++z) {
        bhv[z] = src[qh + 13 - z];
        bwv[z] = src[27 + qw + 13 - z];
      }
    }
  }
  __syncthreads();
  {
    int t = tid;
    if (t < 208) {
      u16* dst = QE + t * 56;
      #pragma unroll
      for (int z = 0; z < 14; ++z) { dst[z] = bhv[z]; dst[14 + z] = bwv[z]; }
      dst[28] = f2b(-30000.0f);
      #pragma unroll
      for (int z = 29; z < 56; ++z) dst[z] = 0;
    }
  }
  // zero this wave's P-tile pad slots (swizzled positions, XOR q4<<4 scheme)
  u16* Pw = PB + wave * 16 * LDP;
  for (int i = lane; i < 16 * 16; i += 64) {
    int r = i >> 4;
    Pw[r * LDP + ((208 + (i & 15)) ^ (((r >> 2) & 3) << 4))] = 0;
  }
  __syncthreads();
  int bI = bnh >> 3, nhI = bnh & 7;
  for (int mf = wave; mf < 13; mf += 8) {
    int qrow = mf * 16 + r16; int qc = qrow < 196 ? qrow : 195;
    int hq = wh * 14 + qc / 14, wq = wwn * 14 + qc % 14;
    const u16* qpg = qkvc + qbase + (size_t)(hq * 56 + wq) * 48;
    const u16* qe = QE + qrow * 56;
    bf16x8 af0 = *reinterpret_cast<const bf16x8*>(qpg + q4 * 8);
    bf16x8 af1;
    if (q4 < 2) af1 = *reinterpret_cast<const bf16x8*>(qpg + 32 + q4 * 8);
    else        af1 = *reinterpret_cast<const bf16x8*>(qe + (q4 - 2) * 8);
    bf16x8 af2 = *reinterpret_cast<const bf16x8*>(qe + 16 + q4 * 8);
    f32x4 s[13];
    #pragma unroll
    for (int nf = 0; nf < 13; ++nf) {
      const u16* kr = KL + (nf * 16 + r16) * LDK;
      bf16x8 b0 = *reinterpret_cast<const bf16x8*>(kr + q4 * 8);
      bf16x8 b1 = *reinterpret_cast<const bf16x8*>(kr + 32 + q4 * 8);
      bf16x8 b2 = *reinterpret_cast<const bf16x8*>(kr + 64 + q4 * 8);
      f32x4 a = {};
      a = MFMA16(af0, b0, a);
      a = MFMA16(af1, b1, a);
      a = MFMA16(af2, b2, a);
      s[nf] = a;
    }
    int rowb = mf * 16 + q4 * 4;
    float mrow[4], den[4];
    #pragma unroll
    for (int j = 0; j < 4; ++j) {
      float mm = s[0][j];
      #pragma unroll
      for (int nf = 1; nf < 13; ++nf) mm = fmaxf(mm, s[nf][j]);
      #pragma unroll
      for (int off = 1; off < 16; off <<= 1) mm = fmaxf(mm, __shfl_xor(mm, off));
      mrow[j] = mm; den[j] = 0.f;
    }
    #pragma unroll
    for (int nf = 0; nf < 13; ++nf) {
      #pragma unroll
      for (int j = 0; j < 4; ++j) {
        float p = __builtin_amdgcn_exp2f(s[nf][j] - mrow[j]);  // raw v_exp_f32
        den[j] += p;
        Pw[(q4 * 4 + j) * LDP + (((nf * 16 + r16) ^ (q4 << 4)))] = f2b(p);
      }
    }
    #pragma unroll
    for (int j = 0; j < 4; ++j)
      #pragma unroll
      for (int off = 1; off < 16; off <<= 1) den[j] += __shfl_xor(den[j], off);
    f32x4 o[3] = {};
    #pragma unroll
    for (int ks = 0; ks < 7; ++ks) {
      bf16x8 ap = *reinterpret_cast<const bf16x8*>(
          Pw + r16 * LDP + ((ks * 32 + q4 * 8) ^ (((r16 >> 2) & 3) << 4)));
      #pragma unroll
      for (int nf3 = 0; nf3 < 3; ++nf3) {
        bf16x8 bv = *reinterpret_cast<const bf16x8*>(VT + (nf3 * 16 + r16) * LDV + ks * 32 + q4 * 8);
        o[nf3] = MFMA16(ap, bv, o[nf3]);
      }
    }
    #pragma unroll
    for (int j = 0; j < 4; ++j) {
      int row = rowb + j;
      if (row < 196) {
        float rden = 1.f / den[j];
        int rh = row / 14;
        int h = wh * 14 + rh, w = wwn * 14 + row - rh * 14;
        int tok = (bI * 56 + h) * 56 + w;
        const u16* qg = qkvc + qbase + (size_t)(h * 56 + w) * 48;
        #pragma unroll
        for (int nf3 = 0; nf3 < 3; ++nf3) {
          int col = nf3 * 16 + r16;
          int cg = nhI * 48 + col;
          obuf[(size_t)(cg >> 5) * (NTOK * 32) + (size_t)tok * 32 + (cg & 31)] =
              f2b(o[nf3][j] * rden + b2f(qg[col]));
        }
      }
    }
  }
}

extern "C" void kernel_launch(void* const* d_in, const int* in_sizes, int n_in,
                              void* d_out, int out_size, void* d_ws, size_t ws_size,
                              hipStream_t stream) {
  const float* x1      = (const float*)d_in[0];
  const float* x2      = (const float*)d_in[1];
  const float* norm1_w = (const float*)d_in[2];
  const float* norm1_b = (const float*)d_in[3];
  const float* qkv_w   = (const float*)d_in[4];
  const float* qkv_b   = (const float*)d_in[5];
  const float* poolq_w = (const float*)d_in[6];
  const float* poolk_w = (const float*)d_in[7];
  const float* poolv_w = (const float*)d_in[8];
  const float* nq_w    = (const float*)d_in[9];
  const float* nq_b    = (const float*)d_in[10];
  const float* nk_w    = (const float*)d_in[11];
  const float* nk_b    = (const float*)d_in[12];
  const float* nv_w    = (const float*)d_in[13];
  const float* nv_b    = (const float*)d_in[14];
  const float* rel_h   = (const float*)d_in[15];
  const float* rel_w   = (const float*)d_in[16];
  const float* proj_w  = (const float*)d_in[17];
  const float* proj_b  = (const float*)d_in[18];
  const float* norm2_w = (const float*)d_in[19];
  const float* norm2_b = (const float*)d_in[20];
  const float* fc1_w   = (const float*)d_in[21];
  const float* fc1_b   = (const float*)d_in[22];
  const float* fc2_w   = (const float*)d_in[23];
  const float* fc2_b   = (const float*)d_in[24];

  // ws overlay (u16 units). Peak = 57,802,752 u16 = 115.6 MB
  u16* ws      = (u16*)d_ws;
  u16* qkv     = ws;                  // [0, 28901376)   qkv bf16, [3,64,3136,48]
  u16* xn      = ws + 28901376;       // LN(x1) bf16, K-blocked [12][25088][32]
  u16* qkvc    = ws + 28901376;       // post conv+LN (after xn dead)
  u16* obuf    = ws;                  // attn out bf16 K-blocked [12][25088][32]
  u16* h1      = ws;                  // gelu(fc1) bf16 K-blocked [48][25088][32]
  u16* yn      = ws + 48168960;       // LN(y1) bf16 K-blocked [12][25088][32]
  u16* qkv_wt  = ws + 38535168;       // bf16 [1152][384] (dies at step 3)
  u16* proj_wt = ws + 9633792;        // bf16 [384][384]  (after qkv dead)
  u16* fc1_wt  = ws + 38535168;       // bf16 [1536][384] (after qkvc dead)
  u16* fc2_wt  = ws + 39124992;       // bf16 [384][1536]
  float* y1 = (float*)d_out;          // 9633792 f32
  float* y2 = y1 + 9633792;

  // 0a. convert qkv weights (transposed [N][K] bf16)
  wcvt_kernel<<<dim3(12, 36), 256, 0, stream>>>(qkv_w, qkv_wt, 384, 1152);
  // 1. xn = LN(x1)  (K-blocked out)
  ln384_kernel<<<NTOK / 4, 256, 0, stream>>>(x1, norm1_w, norm1_b, xn);
  // 2. qkv = xn @ qkv_w + qkv_b  (MFMA, scattered layout; XCD-chunked grid)
  mgemm_kernel<0, 128><<<196 * 9, 256, 0, stream>>>(xn, qkv_wt, qkv_b, nullptr, qkv, NTOK, 1152, 384);
  // 3. q/k/v = LN(dwconv3x3(qkv))  (k pre-scaled by 48^-0.5 * log2e)
  convln_kernel<<<dim3(13, 192), 256, 0, stream>>>(qkv, poolq_w, poolk_w, poolv_w,
                                                   nq_w, nq_b, nk_w, nk_b, nv_w, nv_b, qkvc);
  // 0b. convert proj weights (qkv region now dead)
  wcvt_kernel<<<dim3(12, 12), 256, 0, stream>>>(proj_w, proj_wt, 384, 384);
  // 4. MFMA window attention (+ ori_q residual), K-blocked obuf
  attn_kernel<<<1024, 512, 0, stream>>>(qkvc, rel_h, rel_w, obuf);
  // 0c. convert mlp weights (qkvc region now dead)
  wcvt_kernel<<<dim3(12, 48), 256, 0, stream>>>(fc1_w, fc1_wt, 384, 1536);
  wcvt_kernel<<<dim3(48, 12), 256, 0, stream>>>(fc2_w, fc2_wt, 1536, 384);
  // 5. y1 = x1 + obuf @ proj_w + proj_b  (skinny-N -> BN=64; XCD-chunked)
  mgemm_kernel<1, 64><<<196 * 6, 256, 0, stream>>>(obuf, proj_wt, proj_b, x1, y1, NTOK, 384, 384);
  // 6. yn = LN(y1)  (K-blocked out)
  ln384_kernel<<<NTOK / 4, 256, 0, stream>>>(y1, norm2_w, norm2_b, yn);
  // 7. h1 = gelu(yn @ fc1_w + fc1_b)  (K-blocked out; XCD-chunked)
  mgemm_kernel<2, 128><<<196 * 12, 256, 0, stream>>>(yn, fc1_wt, fc1_b, nullptr, h1, NTOK, 1536, 384);
  // 8. y2 = x2 + h1 @ fc2_w + fc2_b  (skinny-N -> BN=64; XCD-chunked)
  mgemm_kernel<1, 64><<<196 * 6, 256, 0, stream>>>(h1, fc2_wt, fc2_b, x2, y2, NTOK, 384, 1536);
}

// Round 24
// 315.295 us; speedup vs baseline: 1.0512x; 1.0127x over previous
//
#include <hip/hip_runtime.h>
#include <hip/hip_bf16.h>

typedef unsigned short u16;
typedef unsigned int u32;

#define DEVI __device__ __forceinline__

constexpr int BB = 8, HHc = 56, WWc = 56, DIMC = 384, NHC = 8, HDC = 48, WSZ = 14;
constexpr int NTOK = BB * HHc * WWc;          // 25088
constexpr int HIDC = 4 * DIMC;                // 1536
constexpr float EPSF = 1e-5f;
constexpr float SCALEF = 0.14433756729740643f;   // 48^-0.5
constexpr float LOG2E = 1.4426950408889634f;

typedef short bf16x8 __attribute__((ext_vector_type(8)));
typedef float f32x4 __attribute__((ext_vector_type(4)));

// ---- bf16 helpers (raw ushort view) ----
DEVI float b2f(u16 u) { u32 x = ((u32)u) << 16; float f; __builtin_memcpy(&f, &x, 4); return f; }
DEVI float uasf(u32 x) { float f; __builtin_memcpy(&f, &x, 4); return f; }
DEVI u16 f2b(float f) {
  u32 x; __builtin_memcpy(&x, &f, 4);
  u32 r = (x >> 16) & 1u; x += 0x7fffu + r;
  return (u16)(x >> 16);
}

DEVI float wred_sum(float v) {
  #pragma unroll
  for (int o = 32; o; o >>= 1) v += __shfl_xor(v, o);
  return v;
}

// async global->LDS, 16B per lane; dest = uniform base + lane*16
#define GLOAD_LDS16(g, l) __builtin_amdgcn_global_load_lds( \
    (const __attribute__((address_space(1))) u32*)(g), \
    (__attribute__((address_space(3))) u32*)(l), 16, 0, 0)

#define MFMA16(a, b, c) __builtin_amdgcn_mfma_f32_16x16x32_bf16((a), (b), (c), 0, 0, 0)

// ---- weight convert f32 [K][N] -> bf16 [N][K], LDS-tiled transpose ----
__global__ __launch_bounds__(256)
void wcvt_kernel(const float* __restrict__ in, u16* __restrict__ out, int K, int N) {
  __shared__ float t[32][33];
  int bk = blockIdx.x * 32, bn = blockIdx.y * 32;
  int tx = threadIdx.x & 31, ty = threadIdx.x >> 5;
  #pragma unroll
  for (int i = 0; i < 32; i += 8)
    t[ty + i][tx] = in[(size_t)(bk + ty + i) * N + bn + tx];
  __syncthreads();
  #pragma unroll
  for (int i = 0; i < 32; i += 8)
    out[(size_t)(bn + ty + i) * K + bk + tx] = f2b(t[tx][ty + i]);
}

// ---- LayerNorm over 384: f32 in -> bf16 out, K-BLOCKED [12][NTOK][32] ----
__global__ __launch_bounds__(256)
void ln384_kernel(const float* __restrict__ x, const float* __restrict__ w,
                  const float* __restrict__ b, u16* __restrict__ out) {
  int wave = threadIdx.x >> 6, lane = threadIdx.x & 63;
  int tok = blockIdx.x * 4 + wave;
  if (tok >= NTOK) return;
  const float* xr = x + (size_t)tok * DIMC;
  float v[6]; float s = 0.f, ss = 0.f;
  #pragma unroll
  for (int i = 0; i < 6; ++i) {
    v[i] = xr[lane + i * 64];
    s += v[i]; ss += v[i] * v[i];
  }
  s = wred_sum(s); ss = wred_sum(ss);
  float mean = s * (1.f / 384.f);
  float var = ss * (1.f / 384.f) - mean * mean;
  float inv = rsqrtf(var + EPSF);
  #pragma unroll
  for (int i = 0; i < 6; ++i) {
    int c = lane + i * 64;
    out[(size_t)(c >> 5) * (NTOK * 32) + (size_t)tok * 32 + (c & 31)] =
        f2b((v[i] - mean) * inv * w[c] + b[c]);
  }
}

// ---- MFMA GEMM: C[M,N] = A(bf16, K-BLOCKED [K/32][M][32]) @ Wt^T + bias ----
// 128xBN tile, BK=32, 4 waves; 2-buffer LDS, TWO barriers per k-step
// (STAGE -> vmcnt(counted) -> barrier publishes all waves' loads;
//  reads+MFMA -> lgkm(0) -> barrier protects buffer overwrite).
// vmcnt is PER-WAVE: barrier must come AFTER the vmcnt (r18 race lesson).
// Flat grid, col-fastest + chunked XCD swizzle; MODE 0/2 bf16 out via
// LDS-staged coalesced epilogue. BN=64 everywhere it fits (r12/r15 win:
// more co-resident blocks hide the per-k-step barrier drain).
template<int MODE, int BN>
__global__ __launch_bounds__(256)
void mgemm_kernel(const u16* __restrict__ A, const u16* __restrict__ Wt,
                  const float* __restrict__ bias, const float* __restrict__ res,
                  void* __restrict__ outv, int M, int N, int K) {
  constexpr int FN = BN / 32;                    // col frags per wave (4 or 2)
  constexpr int ASZ = 2 * 128 * 32;              // u16; 2 A buffers
  constexpr int BSZ = 2 * BN * 32;               // u16; 2 B buffers
  __shared__ __attribute__((aligned(16))) u16 SM[ASZ + BSZ];
  // ---- chunked XCD swizzle ----
  int nblk = gridDim.x;
  int qch = nblk >> 3, rch = nblk & 7;
  int orig = blockIdx.x;
  int xcd = orig & 7, off = orig >> 3;
  int tile = ((xcd < rch) ? xcd * (qch + 1) : rch * (qch + 1) + (xcd - rch) * qch) + off;
  int ncol = N / BN;
  int brow = tile / ncol, bcol = tile - brow * ncol;   // col-fastest
  int bm0 = brow * 128, bn0 = bcol * BN;
  int tid = threadIdx.x;
  int wave = tid >> 6, lane = tid & 63;
  int wr = wave >> 1, wc = wave & 1;
  int lrow = lane >> 2;
  int slot = (lane & 3) ^ ((lane >> 3) & 3);
  const size_t slab = (size_t)M * 32;            // one k-slab of A
  const u16* ag0 = A + (size_t)(bm0 + wave * 32 + lrow) * 32 + slot * 8;
  const u16* ag1 = ag0 + 16 * 32;
  const u16* bg0 = Wt + (size_t)(bn0 + wave * (BN / 4) + lrow) * K + slot * 8;
  const u16* bg1 = bg0 + (size_t)16 * K;         // used only when BN==128
  int q4 = lane >> 4, r16 = lane & 15;
  int rslot = (q4 ^ ((r16 >> 1) & 3)) * 8;       // de-swizzle on read
  int aoff = (wr * 64 + r16) * 32 + rslot;
  int boff = (wc * (BN / 2) + r16) * 32 + rslot;
  f32x4 acc[4][FN] = {};
  int nk = K >> 5;
  {  // prologue: stage tile 0 into buf 0
    u16* a0 = SM + wave * 1024;
    u16* b0 = SM + ASZ + wave * (BN / 4) * 32;
    GLOAD_LDS16(ag0, a0);  GLOAD_LDS16(ag1, a0 + 512);
    GLOAD_LDS16(bg0, b0);
    if constexpr (BN == 128) GLOAD_LDS16(bg1, b0 + 512);
  }
  int cur = 0;
  for (int t = 0; t < nk; ++t) {
    if (t + 1 < nk) {                            // issue tile t+1 (async)
      int k0 = (t + 1) << 5;
      u16* a0 = SM + (cur ^ 1) * 4096 + wave * 1024;
      u16* b0 = SM + ASZ + (cur ^ 1) * (BN * 32) + wave * (BN / 4) * 32;
      GLOAD_LDS16(ag0 + (size_t)(t + 1) * slab, a0);
      GLOAD_LDS16(ag1 + (size_t)(t + 1) * slab, a0 + 512);
      GLOAD_LDS16(bg0 + k0, b0);
      if constexpr (BN == 128) GLOAD_LDS16(bg1 + k0, b0 + 512);
      if constexpr (BN == 128) asm volatile("s_waitcnt vmcnt(4)" ::: "memory");
      else                     asm volatile("s_waitcnt vmcnt(3)" ::: "memory");
    } else {
      asm volatile("s_waitcnt vmcnt(0)" ::: "memory");
    }
    __builtin_amdgcn_s_barrier();                // ALL waves' tile t landed
    const u16* ar = SM + cur * 4096 + aoff;
    const u16* br = SM + ASZ + cur * (BN * 32) + boff;
    bf16x8 af[4], bf[FN];
    #pragma unroll
    for (int f = 0; f < 4; ++f)
      af[f] = *reinterpret_cast<const bf16x8*>(ar + f * 512);
    #pragma unroll
    for (int f = 0; f < FN; ++f)
      bf[f] = *reinterpret_cast<const bf16x8*>(br + f * 512);
    #pragma unroll
    for (int fm = 0; fm < 4; ++fm)
      #pragma unroll
      for (int fn = 0; fn < FN; ++fn)
        acc[fm][fn] = __builtin_amdgcn_mfma_f32_16x16x32_bf16(af[fm], bf[fn], acc[fm][fn], 0, 0, 0);
    asm volatile("s_waitcnt lgkmcnt(0)" ::: "memory");
    __builtin_amdgcn_s_barrier();                // reads done before overwrite
    cur ^= 1;
  }
  // ---- epilogue. D layout: col=lane&15, row=(lane>>4)*4+j ----
  if constexpr (MODE == 0 || MODE == 2) {
    u16* T = SM;                                 // 128*BN u16 <= ASZ+BSZ
    #pragma unroll
    for (int fm = 0; fm < 4; ++fm) {
      #pragma unroll
      for (int fn = 0; fn < FN; ++fn) {
        int cc = wc * (BN / 2) + fn * 16 + r16;
        float bsv = bias[bn0 + cc];
        #pragma unroll
        for (int j = 0; j < 4; ++j) {
          int rr = wr * 64 + fm * 16 + q4 * 4 + j;
          float v = acc[fm][fn][j] + bsv;
          if constexpr (MODE == 2)
            v = 0.5f * v * (1.0f + erff(v * 0.70710678118654752440f));
          T[rr * BN + cc] = f2b(v);
        }
      }
    }
    __syncthreads();                             // drains ds_writes + barrier
    constexpr int CPR = BN / 8;                  // 16B chunks per row
    u16* out = (u16*)outv;
    #pragma unroll
    for (int i = 0; i < 128 * CPR / 256; ++i) {
      int idx = i * 256 + tid;
      int row = idx / CPR, col8 = (idx - row * CPR) * 8;
      uint4 v = *reinterpret_cast<const uint4*>(T + row * BN + col8);
      int c = bn0 + col8;
      int r = bm0 + row;
      if constexpr (MODE == 0) {
        int s = c / DIMC; int rem = c - s * DIMC;
        int nh = rem / HDC; int ch = rem - nh * HDC;
        int b = r / 3136; int hw = r - b * 3136;
        *reinterpret_cast<uint4*>(
            out + (((size_t)(s * 64 + b * 8 + nh)) * 3136 + hw) * 48 + ch) = v;
      } else {
        *reinterpret_cast<uint4*>(
            out + (size_t)(c >> 5) * M * 32 + (size_t)r * 32 + (c & 31)) = v;
      }
    }
  } else {
    int c0 = bn0 + wc * (BN / 2) + r16;
    int r0 = bm0 + wr * 64 + q4 * 4;
    #pragma unroll
    for (int fm = 0; fm < 4; ++fm) {
      #pragma unroll
      for (int fn = 0; fn < FN; ++fn) {
        int c = c0 + fn * 16;
        float bsv = bias[c];
        #pragma unroll
        for (int j = 0; j < 4; ++j) {
          int r = r0 + fm * 16 + j;
          float v = acc[fm][fn][j] + bsv;
          float* out = (float*)outv;
          size_t idx = (size_t)r * N + c;
          out[idx] = v + res[idx];
        }
      }
    }
  }
}

// ---- depthwise 3x3 conv (pad 1) + LayerNorm over 48 channels ----
// k-branch (s==1) gamma/beta pre-scaled by 48^-0.5 * log2(e): folds both the
// QK^T scale AND the softmax exp->exp2 conversion into this LN.
__global__ __launch_bounds__(256)
void convln_kernel(const u16* __restrict__ qkv,
                   const float* __restrict__ wq, const float* __restrict__ wk, const float* __restrict__ wv,
                   const float* __restrict__ gq, const float* __restrict__ bq,
                   const float* __restrict__ gk, const float* __restrict__ bk,
                   const float* __restrict__ gv, const float* __restrict__ bv,
                   u16* __restrict__ out) {
  __shared__ __attribute__((aligned(16))) float wsm[432];
  __shared__ __attribute__((aligned(16))) float gsm[48];
  __shared__ __attribute__((aligned(16))) float bsm[48];
  int tid = threadIdx.x;
  int sb = blockIdx.y;                  // 0..191 = s*64 + bnh
  int s = sb >> 6;
  const float* wgt = (s == 0) ? wq : ((s == 1) ? wk : wv);
  const float* gam = (s == 0) ? gq : ((s == 1) ? gk : gv);
  const float* bet = (s == 0) ? bq : ((s == 1) ? bk : bv);
  float sc = (s == 1) ? SCALEF * LOG2E : 1.0f;
  for (int i = tid; i < 432; i += 256) wsm[i] = wgt[i];
  if (tid < 48) { gsm[tid] = gam[tid] * sc; bsm[tid] = bet[tid] * sc; }
  __syncthreads();
  int hw = blockIdx.x * 256 + tid;
  if (hw >= 3136) return;
  int h = hw / 56, w = hw - h * 56;
  const u16* img = qkv + (size_t)sb * (3136 * 48);
  float acc[48];
  #pragma unroll
  for (int c = 0; c < 48; ++c) acc[c] = 0.f;
  #pragma unroll
  for (int dy = -1; dy <= 1; ++dy) {
    int hh = h + dy;
    if ((unsigned)hh >= 56u) continue;
    #pragma unroll
    for (int dx = -1; dx <= 1; ++dx) {
      int ww = w + dx;
      if ((unsigned)ww >= 56u) continue;
      const uint4* p = reinterpret_cast<const uint4*>(img + (size_t)(hh * 56 + ww) * 48);
      const float4* wr = reinterpret_cast<const float4*>(wsm + ((dy + 1) * 3 + (dx + 1)) * 48);
      #pragma unroll
      for (int g = 0; g < 6; ++g) {
        uint4 v = p[g];
        float4 w0 = wr[g * 2], w1 = wr[g * 2 + 1];
        acc[g * 8 + 0] += uasf(v.x << 16)          * w0.x;
        acc[g * 8 + 1] += uasf(v.x & 0xFFFF0000u)  * w0.y;
        acc[g * 8 + 2] += uasf(v.y << 16)          * w0.z;
        acc[g * 8 + 3] += uasf(v.y & 0xFFFF0000u)  * w0.w;
        acc[g * 8 + 4] += uasf(v.z << 16)          * w1.x;
        acc[g * 8 + 5] += uasf(v.z & 0xFFFF0000u)  * w1.y;
        acc[g * 8 + 6] += uasf(v.w << 16)          * w1.z;
        acc[g * 8 + 7] += uasf(v.w & 0xFFFF0000u)  * w1.w;
      }
    }
  }
  float sum = 0.f, ssq = 0.f;
  #pragma unroll
  for (int c = 0; c < 48; ++c) { sum += acc[c]; ssq += acc[c] * acc[c]; }
  float mean = sum * (1.f / 48.f);
  float var = ssq * (1.f / 48.f) - mean * mean;
  float inv = rsqrtf(var + EPSF);
  u16* op = out + ((size_t)sb * 3136 + hw) * 48;
  #pragma unroll
  for (int g = 0; g < 6; ++g) {
    const float4 gm0 = *reinterpret_cast<const float4*>(gsm + g * 8);
    const float4 gm1 = *reinterpret_cast<const float4*>(gsm + g * 8 + 4);
    const float4 bt0 = *reinterpret_cast<const float4*>(bsm + g * 8);
    const float4 bt1 = *reinterpret_cast<const float4*>(bsm + g * 8 + 4);
    uint4 ov;
    u32 a0 = f2b((acc[g * 8 + 0] - mean) * inv * gm0.x + bt0.x);
    u32 a1 = f2b((acc[g * 8 + 1] - mean) * inv * gm0.y + bt0.y);
    u32 a2 = f2b((acc[g * 8 + 2] - mean) * inv * gm0.z + bt0.z);
    u32 a3 = f2b((acc[g * 8 + 3] - mean) * inv * gm0.w + bt0.w);
    u32 a4 = f2b((acc[g * 8 + 4] - mean) * inv * gm1.x + bt1.x);
    u32 a5 = f2b((acc[g * 8 + 5] - mean) * inv * gm1.y + bt1.y);
    u32 a6 = f2b((acc[g * 8 + 6] - mean) * inv * gm1.z + bt1.z);
    u32 a7 = f2b((acc[g * 8 + 7] - mean) * inv * gm1.w + bt1.w);
    ov.x = a0 | (a1 << 16);
    ov.y = a2 | (a3 << 16);
    ov.z = a4 | (a5 << 16);
    ov.w = a6 | (a7 << 16);
    *reinterpret_cast<uint4*>(op + g * 8) = ov;
  }
}

// ---- MFMA window attention, extended-K bias fold, log2-domain softmax ----
// Scores arrive as log2e * s_orig (k and Rel pre-scaled); p computed via the
// RAW v_exp_f32 (__builtin_amdgcn_exp2f) -- exp2f() is the slow precise OCML
// path (r20 lesson). P tiles: LDP=256 + XOR(q4<<4).
constexpr int LDP = 256;
constexpr int LDK = 104;
constexpr int LDV = 228;
__global__ __launch_bounds__(512, 1)
void attn_kernel(const u16* __restrict__ qkvc, const float* __restrict__ rel_h,
                 const float* __restrict__ rel_w, u16* __restrict__ obuf) {
  __shared__ __attribute__((aligned(16))) u16 KL[208 * LDK];
  __shared__ __attribute__((aligned(16))) u16 VT[48 * LDV];
  __shared__ __attribute__((aligned(16))) u16 QE[208 * 56];
  __shared__ __attribute__((aligned(16))) u16 PB[8 * 16 * LDP];

  int wid = blockIdx.x;
  int bnh = wid >> 4, wrem = wid & 15, wh = wrem >> 2, wwn = wrem & 3;
  int tid = threadIdx.x;
  int wave = tid >> 6, lane = tid & 63;
  int q4 = lane >> 4, r16 = lane & 15;

  { u32* z;
    z = (u32*)KL; for (int i = tid; i < 208 * LDK / 2; i += 512) z[i] = 0;
    z = (u32*)VT; for (int i = tid; i < 48 * LDV / 2; i += 512) z[i] = 0;
    // QRW B-operand reads PB rows 0..63 x cols 0..63 (stride 72); LDS start
    // state undefined; 0*NaN=NaN -> must zero the region.
    z = (u32*)PB; for (int i = tid; i < 64 * 72 / 2; i += 512) z[i] = 0;
  }
  __syncthreads();
  size_t qbase = (size_t)bnh * 3136 * 48;
  size_t kbase = ((size_t)(64 + bnh) * 3136) * 48;
  size_t vbase = ((size_t)(128 + bnh) * 3136) * 48;
  for (int i = tid; i < 196 * 12; i += 512) {
    int r = i / 12, c4 = (i - r * 12) * 4;
    int h = wh * 14 + r / 14, w = wwn * 14 + r % 14;
    size_t g = (size_t)(h * 56 + w) * 48 + c4;
    ushort4 kv = *reinterpret_cast<const ushort4*>(qkvc + kbase + g);
    *reinterpret_cast<ushort4*>(KL + r * LDK + c4) = kv;   // pre-scaled k
    ushort4 vv = *reinterpret_cast<const ushort4*>(qkvc + vbase + g);
    VT[(c4 + 0) * LDV + r] = vv.x; VT[(c4 + 1) * LDV + r] = vv.y;
    VT[(c4 + 2) * LDV + r] = vv.z; VT[(c4 + 3) * LDV + r] = vv.w;
  }
  // K one-hot / mask flag columns (bf16 1.0 = 0x3F80)
  for (int r = tid; r < 208; r += 512) {
    if (r < 196) {
      KL[r * LDK + 48 + r / 14] = 0x3F80;
      KL[r * LDK + 62 + r % 14] = 0x3F80;
    } else {
      KL[r * LDK + 76] = 0x3F80;
    }
  }
  // Rel staged *log2e so QE bias tables are in log2 domain
  for (int i = tid; i < 54 * 48; i += 512) {
    int r = i / 48, c = i - r * 48;
    float v = (r < 27) ? rel_h[r * 48 + c] : rel_w[(r - 27) * 48 + c];
    PB[r * 72 + c] = f2b(v * LOG2E);
  }
  __syncthreads();
  // QE = Q @ Rel^T
  for (int mf = wave; mf < 13; mf += 8) {
    int qrow = mf * 16 + r16; int qc = qrow < 196 ? qrow : 195;
    int hq = wh * 14 + qc / 14, wq = wwn * 14 + qc % 14;
    const u16* qpg = qkvc + qbase + (size_t)(hq * 56 + wq) * 48;
    bf16x8 af0 = *reinterpret_cast<const bf16x8*>(qpg + q4 * 8);
    bf16x8 af1 = {0, 0, 0, 0, 0, 0, 0, 0};
    if (q4 < 2) af1 = *reinterpret_cast<const bf16x8*>(qpg + 32 + q4 * 8);
    #pragma unroll
    for (int nf = 0; nf < 4; ++nf) {
      bf16x8 b0 = *reinterpret_cast<const bf16x8*>(PB + (nf * 16 + r16) * 72 + q4 * 8);
      bf16x8 b1 = *reinterpret_cast<const bf16x8*>(PB + (nf * 16 + r16) * 72 + 32 + q4 * 8);
      f32x4 acc = {};
      acc = MFMA16(af0, b0, acc);
      acc = MFMA16(af1, b1, acc);
      int col = nf * 16 + r16;
      if (col < 54) {
        #pragma unroll
        for (int j = 0; j < 4; ++j)
          QE[(mf * 16 + q4 * 4 + j) * 56 + col] = f2b(acc[j]);
      }
    }
  }
  __syncthreads();
  u16 bhv[14], bwv[14];
  {
    int t = tid;
    if (t < 208) {
      int qc = t < 196 ? t : 195;
      int qh = qc / 14, qw = qc - qh * 14;
      const u16* src = QE + t * 56;
      #pragma unroll
      for (int z = 0; z < 14; ++z) {
        bhv[z] = src[qh + 13 - z];
        bwv[z] = src[27 + qw + 13 - z];
      }
    }
  }
  __syncthreads();
  {
    int t = tid;
    if (t < 208) {
      u16* dst = QE + t * 56;
      #pragma unroll
      for (int z = 0; z < 14; ++z) { dst[z] = bhv[z]; dst[14 + z] = bwv[z]; }
      dst[28] = f2b(-30000.0f);
      #pragma unroll
      for (int z = 29; z < 56; ++z) dst[z] = 0;
    }
  }
  // zero this wave's P-tile pad slots (swizzled positions, XOR q4<<4 scheme)
  u16* Pw = PB + wave * 16 * LDP;
  for (int i = lane; i < 16 * 16; i += 64) {
    int r = i >> 4;
    Pw[r * LDP + ((208 + (i & 15)) ^ (((r >> 2) & 3) << 4))] = 0;
  }
  __syncthreads();
  int bI = bnh >> 3, nhI = bnh & 7;
  for (int mf = wave; mf < 13; mf += 8) {
    int qrow = mf * 16 + r16; int qc = qrow < 196 ? qrow : 195;
    int hq = wh * 14 + qc / 14, wq = wwn * 14 + qc % 14;
    const u16* qpg = qkvc + qbase + (size_t)(hq * 56 + wq) * 48;
    const u16* qe = QE + qrow * 56;
    bf16x8 af0 = *reinterpret_cast<const bf16x8*>(qpg + q4 * 8);
    bf16x8 af1;
    if (q4 < 2) af1 = *reinterpret_cast<const bf16x8*>(qpg + 32 + q4 * 8);
    else        af1 = *reinterpret_cast<const bf16x8*>(qe + (q4 - 2) * 8);
    bf16x8 af2 = *reinterpret_cast<const bf16x8*>(qe + 16 + q4 * 8);
    f32x4 s[13];
    #pragma unroll
    for (int nf = 0; nf < 13; ++nf) {
      const u16* kr = KL + (nf * 16 + r16) * LDK;
      bf16x8 b0 = *reinterpret_cast<const bf16x8*>(kr + q4 * 8);
      bf16x8 b1 = *reinterpret_cast<const bf16x8*>(kr + 32 + q4 * 8);
      bf16x8 b2 = *reinterpret_cast<const bf16x8*>(kr + 64 + q4 * 8);
      f32x4 a = {};
      a = MFMA16(af0, b0, a);
      a = MFMA16(af1, b1, a);
      a = MFMA16(af2, b2, a);
      s[nf] = a;
    }
    int rowb = mf * 16 + q4 * 4;
    float mrow[4], den[4];
    #pragma unroll
    for (int j = 0; j < 4; ++j) {
      float mm = s[0][j];
      #pragma unroll
      for (int nf = 1; nf < 13; ++nf) mm = fmaxf(mm, s[nf][j]);
      #pragma unroll
      for (int off = 1; off < 16; off <<= 1) mm = fmaxf(mm, __shfl_xor(mm, off));
      mrow[j] = mm; den[j] = 0.f;
    }
    #pragma unroll
    for (int nf = 0; nf < 13; ++nf) {
      #pragma unroll
      for (int j = 0; j < 4; ++j) {
        float p = __builtin_amdgcn_exp2f(s[nf][j] - mrow[j]);  // raw v_exp_f32
        den[j] += p;
        Pw[(q4 * 4 + j) * LDP + (((nf * 16 + r16) ^ (q4 << 4)))] = f2b(p);
      }
    }
    #pragma unroll
    for (int j = 0; j < 4; ++j)
      #pragma unroll
      for (int off = 1; off < 16; off <<= 1) den[j] += __shfl_xor(den[j], off);
    f32x4 o[3] = {};
    #pragma unroll
    for (int ks = 0; ks < 7; ++ks) {
      bf16x8 ap = *reinterpret_cast<const bf16x8*>(
          Pw + r16 * LDP + ((ks * 32 + q4 * 8) ^ (((r16 >> 2) & 3) << 4)));
      #pragma unroll
      for (int nf3 = 0; nf3 < 3; ++nf3) {
        bf16x8 bv = *reinterpret_cast<const bf16x8*>(VT + (nf3 * 16 + r16) * LDV + ks * 32 + q4 * 8);
        o[nf3] = MFMA16(ap, bv, o[nf3]);
      }
    }
    #pragma unroll
    for (int j = 0; j < 4; ++j) {
      int row = rowb + j;
      if (row < 196) {
        float rden = 1.f / den[j];
        int rh = row / 14;
        int h = wh * 14 + rh, w = wwn * 14 + row - rh * 14;
        int tok = (bI * 56 + h) * 56 + w;
        const u16* qg = qkvc + qbase + (size_t)(h * 56 + w) * 48;
        #pragma unroll
        for (int nf3 = 0; nf3 < 3; ++nf3) {
          int col = nf3 * 16 + r16;
          int cg = nhI * 48 + col;
          obuf[(size_t)(cg >> 5) * (NTOK * 32) + (size_t)tok * 32 + (cg & 31)] =
              f2b(o[nf3][j] * rden + b2f(qg[col]));
        }
      }
    }
  }
}

extern "C" void kernel_launch(void* const* d_in, const int* in_sizes, int n_in,
                              void* d_out, int out_size, void* d_ws, size_t ws_size,
                              hipStream_t stream) {
  const float* x1      = (const float*)d_in[0];
  const float* x2      = (const float*)d_in[1];
  const float* norm1_w = (const float*)d_in[2];
  const float* norm1_b = (const float*)d_in[3];
  const float* qkv_w   = (const float*)d_in[4];
  const float* qkv_b   = (const float*)d_in[5];
  const float* poolq_w = (const float*)d_in[6];
  const float* poolk_w = (const float*)d_in[7];
  const float* poolv_w = (const float*)d_in[8];
  const float* nq_w    = (const float*)d_in[9];
  const float* nq_b    = (const float*)d_in[10];
  const float* nk_w    = (const float*)d_in[11];
  const float* nk_b    = (const float*)d_in[12];
  const float* nv_w    = (const float*)d_in[13];
  const float* nv_b    = (const float*)d_in[14];
  const float* rel_h   = (const float*)d_in[15];
  const float* rel_w   = (const float*)d_in[16];
  const float* proj_w  = (const float*)d_in[17];
  const float* proj_b  = (const float*)d_in[18];
  const float* norm2_w = (const float*)d_in[19];
  const float* norm2_b = (const float*)d_in[20];
  const float* fc1_w   = (const float*)d_in[21];
  const float* fc1_b   = (const float*)d_in[22];
  const float* fc2_w   = (const float*)d_in[23];
  const float* fc2_b   = (const float*)d_in[24];

  // ws overlay (u16 units). Peak = 57,802,752 u16 = 115.6 MB
  u16* ws      = (u16*)d_ws;
  u16* qkv     = ws;                  // [0, 28901376)   qkv bf16, [3,64,3136,48]
  u16* xn      = ws + 28901376;       // LN(x1) bf16, K-blocked [12][25088][32]
  u16* qkvc    = ws + 28901376;       // post conv+LN (after xn dead)
  u16* obuf    = ws;                  // attn out bf16 K-blocked [12][25088][32]
  u16* h1      = ws;                  // gelu(fc1) bf16 K-blocked [48][25088][32]
  u16* yn      = ws + 48168960;       // LN(y1) bf16 K-blocked [12][25088][32]
  u16* qkv_wt  = ws + 38535168;       // bf16 [1152][384] (dies at step 3)
  u16* proj_wt = ws + 9633792;        // bf16 [384][384]  (after qkv dead)
  u16* fc1_wt  = ws + 38535168;       // bf16 [1536][384] (after qkvc dead)
  u16* fc2_wt  = ws + 39124992;       // bf16 [384][1536]
  float* y1 = (float*)d_out;          // 9633792 f32
  float* y2 = y1 + 9633792;

  // 0a. convert qkv weights (transposed [N][K] bf16)
  wcvt_kernel<<<dim3(12, 36), 256, 0, stream>>>(qkv_w, qkv_wt, 384, 1152);
  // 1. xn = LN(x1)  (K-blocked out)
  ln384_kernel<<<NTOK / 4, 256, 0, stream>>>(x1, norm1_w, norm1_b, xn);
  // 2. qkv = xn @ qkv_w + qkv_b  (BN=64: more co-resident blocks)
  mgemm_kernel<0, 64><<<196 * 18, 256, 0, stream>>>(xn, qkv_wt, qkv_b, nullptr, qkv, NTOK, 1152, 384);
  // 3. q/k/v = LN(dwconv3x3(qkv))  (k pre-scaled by 48^-0.5 * log2e)
  convln_kernel<<<dim3(13, 192), 256, 0, stream>>>(qkv, poolq_w, poolk_w, poolv_w,
                                                   nq_w, nq_b, nk_w, nk_b, nv_w, nv_b, qkvc);
  // 0b. convert proj weights (qkv region now dead)
  wcvt_kernel<<<dim3(12, 12), 256, 0, stream>>>(proj_w, proj_wt, 384, 384);
  // 4. MFMA window attention (+ ori_q residual), K-blocked obuf
  attn_kernel<<<1024, 512, 0, stream>>>(qkvc, rel_h, rel_w, obuf);
  // 0c. convert mlp weights (qkvc region now dead)
  wcvt_kernel<<<dim3(12, 48), 256, 0, stream>>>(fc1_w, fc1_wt, 384, 1536);
  wcvt_kernel<<<dim3(48, 12), 256, 0, stream>>>(fc2_w, fc2_wt, 1536, 384);
  // 5. y1 = x1 + obuf @ proj_w + proj_b  (BN=64; XCD-chunked)
  mgemm_kernel<1, 64><<<196 * 6, 256, 0, stream>>>(obuf, proj_wt, proj_b, x1, y1, NTOK, 384, 384);
  // 6. yn = LN(y1)  (K-blocked out)
  ln384_kernel<<<NTOK / 4, 256, 0, stream>>>(y1, norm2_w, norm2_b, yn);
  // 7. h1 = gelu(yn @ fc1_w + fc1_b)  (BN=64; K-blocked out; XCD-chunked)
  mgemm_kernel<2, 64><<<196 * 24, 256, 0, stream>>>(yn, fc1_wt, fc1_b, nullptr, h1, NTOK, 1536, 384);
  // 8. y2 = x2 + h1 @ fc2_w + fc2_b  (BN=64; XCD-chunked)
  mgemm_kernel<1, 64><<<196 * 6, 256, 0, stream>>>(h1, fc2_wt, fc2_b, x2, y2, NTOK, 384, 1536);
}

// Round 25
// 313.154 us; speedup vs baseline: 1.0584x; 1.0068x over previous
//
#include <hip/hip_runtime.h>
#include <hip/hip_bf16.h>

typedef unsigned short u16;
typedef unsigned int u32;

#define DEVI __device__ __forceinline__

constexpr int BB = 8, HHc = 56, WWc = 56, DIMC = 384, NHC = 8, HDC = 48, WSZ = 14;
constexpr int NTOK = BB * HHc * WWc;          // 25088
constexpr int HIDC = 4 * DIMC;                // 1536
constexpr float EPSF = 1e-5f;
constexpr float SCALEF = 0.14433756729740643f;   // 48^-0.5
constexpr float LOG2E = 1.4426950408889634f;

typedef short bf16x8 __attribute__((ext_vector_type(8)));
typedef float f32x4 __attribute__((ext_vector_type(4)));

// ---- bf16 helpers (raw ushort view) ----
DEVI float b2f(u16 u) { u32 x = ((u32)u) << 16; float f; __builtin_memcpy(&f, &x, 4); return f; }
DEVI float uasf(u32 x) { float f; __builtin_memcpy(&f, &x, 4); return f; }
DEVI u16 f2b(float f) {
  u32 x; __builtin_memcpy(&x, &f, 4);
  u32 r = (x >> 16) & 1u; x += 0x7fffu + r;
  return (u16)(x >> 16);
}

DEVI float wred_sum(float v) {
  #pragma unroll
  for (int o = 32; o; o >>= 1) v += __shfl_xor(v, o);
  return v;
}

// bijective chunked XCD swizzle (nblk % 8 == 0 fast path else general)
DEVI int xcd_chunk(int orig, int nblk) {
  int qch = nblk >> 3, rch = nblk & 7;
  int xcd = orig & 7, off = orig >> 3;
  return ((xcd < rch) ? xcd * (qch + 1) : rch * (qch + 1) + (xcd - rch) * qch) + off;
}

// async global->LDS, 16B per lane; dest = uniform base + lane*16
#define GLOAD_LDS16(g, l) __builtin_amdgcn_global_load_lds( \
    (const __attribute__((address_space(1))) u32*)(g), \
    (__attribute__((address_space(3))) u32*)(l), 16, 0, 0)

#define MFMA16(a, b, c) __builtin_amdgcn_mfma_f32_16x16x32_bf16((a), (b), (c), 0, 0, 0)

// ---- weight convert f32 [K][N] -> bf16 [N][K], LDS-tiled transpose ----
__global__ __launch_bounds__(256)
void wcvt_kernel(const float* __restrict__ in, u16* __restrict__ out, int K, int N) {
  __shared__ float t[32][33];
  int bk = blockIdx.x * 32, bn = blockIdx.y * 32;
  int tx = threadIdx.x & 31, ty = threadIdx.x >> 5;
  #pragma unroll
  for (int i = 0; i < 32; i += 8)
    t[ty + i][tx] = in[(size_t)(bk + ty + i) * N + bn + tx];
  __syncthreads();
  #pragma unroll
  for (int i = 0; i < 32; i += 8)
    out[(size_t)(bn + ty + i) * K + bk + tx] = f2b(t[tx][ty + i]);
}

// ---- LayerNorm over 384: f32 in -> bf16 out, K-BLOCKED [12][NTOK][32] ----
__global__ __launch_bounds__(256)
void ln384_kernel(const float* __restrict__ x, const float* __restrict__ w,
                  const float* __restrict__ b, u16* __restrict__ out) {
  int wave = threadIdx.x >> 6, lane = threadIdx.x & 63;
  int tok = blockIdx.x * 4 + wave;
  if (tok >= NTOK) return;
  const float* xr = x + (size_t)tok * DIMC;
  float v[6]; float s = 0.f, ss = 0.f;
  #pragma unroll
  for (int i = 0; i < 6; ++i) {
    v[i] = xr[lane + i * 64];
    s += v[i]; ss += v[i] * v[i];
  }
  s = wred_sum(s); ss = wred_sum(ss);
  float mean = s * (1.f / 384.f);
  float var = ss * (1.f / 384.f) - mean * mean;
  float inv = rsqrtf(var + EPSF);
  #pragma unroll
  for (int i = 0; i < 6; ++i) {
    int c = lane + i * 64;
    out[(size_t)(c >> 5) * (NTOK * 32) + (size_t)tok * 32 + (c & 31)] =
        f2b((v[i] - mean) * inv * w[c] + b[c]);
  }
}

// ---- MFMA GEMM: C[M,N] = A(bf16, K-BLOCKED [K/32][M][32]) @ Wt^T + bias ----
// 128xBN tile, BK=32, 4 waves; 2-buffer LDS, TWO barriers per k-step
// (STAGE -> vmcnt(counted) -> barrier publishes all waves' loads;
//  reads+MFMA -> lgkm(0) -> barrier protects buffer overwrite).
// vmcnt is PER-WAVE: barrier must come AFTER the vmcnt (r18 race lesson).
// Flat grid, col-fastest + chunked XCD swizzle; MODE 0/2 bf16 out via
// LDS-staged coalesced epilogue. BN=64 everywhere (r12/r24 win).
template<int MODE, int BN>
__global__ __launch_bounds__(256)
void mgemm_kernel(const u16* __restrict__ A, const u16* __restrict__ Wt,
                  const float* __restrict__ bias, const float* __restrict__ res,
                  void* __restrict__ outv, int M, int N, int K) {
  constexpr int FN = BN / 32;                    // col frags per wave (4 or 2)
  constexpr int ASZ = 2 * 128 * 32;              // u16; 2 A buffers
  constexpr int BSZ = 2 * BN * 32;               // u16; 2 B buffers
  __shared__ __attribute__((aligned(16))) u16 SM[ASZ + BSZ];
  int tile = xcd_chunk(blockIdx.x, gridDim.x);
  int ncol = N / BN;
  int brow = tile / ncol, bcol = tile - brow * ncol;   // col-fastest
  int bm0 = brow * 128, bn0 = bcol * BN;
  int tid = threadIdx.x;
  int wave = tid >> 6, lane = tid & 63;
  int wr = wave >> 1, wc = wave & 1;
  int lrow = lane >> 2;
  int slot = (lane & 3) ^ ((lane >> 3) & 3);
  const size_t slab = (size_t)M * 32;            // one k-slab of A
  const u16* ag0 = A + (size_t)(bm0 + wave * 32 + lrow) * 32 + slot * 8;
  const u16* ag1 = ag0 + 16 * 32;
  const u16* bg0 = Wt + (size_t)(bn0 + wave * (BN / 4) + lrow) * K + slot * 8;
  const u16* bg1 = bg0 + (size_t)16 * K;         // used only when BN==128
  int q4 = lane >> 4, r16 = lane & 15;
  int rslot = (q4 ^ ((r16 >> 1) & 3)) * 8;       // de-swizzle on read
  int aoff = (wr * 64 + r16) * 32 + rslot;
  int boff = (wc * (BN / 2) + r16) * 32 + rslot;
  f32x4 acc[4][FN] = {};
  int nk = K >> 5;
  {  // prologue: stage tile 0 into buf 0
    u16* a0 = SM + wave * 1024;
    u16* b0 = SM + ASZ + wave * (BN / 4) * 32;
    GLOAD_LDS16(ag0, a0);  GLOAD_LDS16(ag1, a0 + 512);
    GLOAD_LDS16(bg0, b0);
    if constexpr (BN == 128) GLOAD_LDS16(bg1, b0 + 512);
  }
  int cur = 0;
  for (int t = 0; t < nk; ++t) {
    if (t + 1 < nk) {                            // issue tile t+1 (async)
      int k0 = (t + 1) << 5;
      u16* a0 = SM + (cur ^ 1) * 4096 + wave * 1024;
      u16* b0 = SM + ASZ + (cur ^ 1) * (BN * 32) + wave * (BN / 4) * 32;
      GLOAD_LDS16(ag0 + (size_t)(t + 1) * slab, a0);
      GLOAD_LDS16(ag1 + (size_t)(t + 1) * slab, a0 + 512);
      GLOAD_LDS16(bg0 + k0, b0);
      if constexpr (BN == 128) GLOAD_LDS16(bg1 + k0, b0 + 512);
      if constexpr (BN == 128) asm volatile("s_waitcnt vmcnt(4)" ::: "memory");
      else                     asm volatile("s_waitcnt vmcnt(3)" ::: "memory");
    } else {
      asm volatile("s_waitcnt vmcnt(0)" ::: "memory");
    }
    __builtin_amdgcn_s_barrier();                // ALL waves' tile t landed
    const u16* ar = SM + cur * 4096 + aoff;
    const u16* br = SM + ASZ + cur * (BN * 32) + boff;
    bf16x8 af[4], bf[FN];
    #pragma unroll
    for (int f = 0; f < 4; ++f)
      af[f] = *reinterpret_cast<const bf16x8*>(ar + f * 512);
    #pragma unroll
    for (int f = 0; f < FN; ++f)
      bf[f] = *reinterpret_cast<const bf16x8*>(br + f * 512);
    #pragma unroll
    for (int fm = 0; fm < 4; ++fm)
      #pragma unroll
      for (int fn = 0; fn < FN; ++fn)
        acc[fm][fn] = __builtin_amdgcn_mfma_f32_16x16x32_bf16(af[fm], bf[fn], acc[fm][fn], 0, 0, 0);
    asm volatile("s_waitcnt lgkmcnt(0)" ::: "memory");
    __builtin_amdgcn_s_barrier();                // reads done before overwrite
    cur ^= 1;
  }
  // ---- epilogue. D layout: col=lane&15, row=(lane>>4)*4+j ----
  if constexpr (MODE == 0 || MODE == 2) {
    u16* T = SM;                                 // 128*BN u16 <= ASZ+BSZ
    #pragma unroll
    for (int fm = 0; fm < 4; ++fm) {
      #pragma unroll
      for (int fn = 0; fn < FN; ++fn) {
        int cc = wc * (BN / 2) + fn * 16 + r16;
        float bsv = bias[bn0 + cc];
        #pragma unroll
        for (int j = 0; j < 4; ++j) {
          int rr = wr * 64 + fm * 16 + q4 * 4 + j;
          float v = acc[fm][fn][j] + bsv;
          if constexpr (MODE == 2)
            v = 0.5f * v * (1.0f + erff(v * 0.70710678118654752440f));
          T[rr * BN + cc] = f2b(v);
        }
      }
    }
    __syncthreads();                             // drains ds_writes + barrier
    constexpr int CPR = BN / 8;                  // 16B chunks per row
    u16* out = (u16*)outv;
    #pragma unroll
    for (int i = 0; i < 128 * CPR / 256; ++i) {
      int idx = i * 256 + tid;
      int row = idx / CPR, col8 = (idx - row * CPR) * 8;
      uint4 v = *reinterpret_cast<const uint4*>(T + row * BN + col8);
      int c = bn0 + col8;
      int r = bm0 + row;
      if constexpr (MODE == 0) {
        int s = c / DIMC; int rem = c - s * DIMC;
        int nh = rem / HDC; int ch = rem - nh * HDC;
        int b = r / 3136; int hw = r - b * 3136;
        *reinterpret_cast<uint4*>(
            out + (((size_t)(s * 64 + b * 8 + nh)) * 3136 + hw) * 48 + ch) = v;
      } else {
        *reinterpret_cast<uint4*>(
            out + (size_t)(c >> 5) * M * 32 + (size_t)r * 32 + (c & 31)) = v;
      }
    }
  } else {
    int c0 = bn0 + wc * (BN / 2) + r16;
    int r0 = bm0 + wr * 64 + q4 * 4;
    #pragma unroll
    for (int fm = 0; fm < 4; ++fm) {
      #pragma unroll
      for (int fn = 0; fn < FN; ++fn) {
        int c = c0 + fn * 16;
        float bsv = bias[c];
        #pragma unroll
        for (int j = 0; j < 4; ++j) {
          int r = r0 + fm * 16 + j;
          float v = acc[fm][fn][j] + bsv;
          float* out = (float*)outv;
          size_t idx = (size_t)r * N + c;
          out[idx] = v + res[idx];
        }
      }
    }
  }
}

// ---- depthwise 3x3 conv (pad 1) + LayerNorm over 48 channels ----
// k-branch (s==1) gamma/beta pre-scaled by 48^-0.5 * log2(e).
// FLAT 1D grid + chunked XCD swizzle: the 13 blocks sharing one sb's 301KB
// image panel stay on ONE XCD -> panel fetched once per L2, not 8x.
__global__ __launch_bounds__(256)
void convln_kernel(const u16* __restrict__ qkv,
                   const float* __restrict__ wq, const float* __restrict__ wk, const float* __restrict__ wv,
                   const float* __restrict__ gq, const float* __restrict__ bq,
                   const float* __restrict__ gk, const float* __restrict__ bk,
                   const float* __restrict__ gv, const float* __restrict__ bv,
                   u16* __restrict__ out) {
  __shared__ __attribute__((aligned(16))) float wsm[432];
  __shared__ __attribute__((aligned(16))) float gsm[48];
  __shared__ __attribute__((aligned(16))) float bsm[48];
  int tid = threadIdx.x;
  int tile = xcd_chunk(blockIdx.x, gridDim.x);  // 2496 = 13 * 192
  int sb = tile / 13, xb = tile - sb * 13;      // sb-major: same-panel adjacent
  int s = sb >> 6;
  const float* wgt = (s == 0) ? wq : ((s == 1) ? wk : wv);
  const float* gam = (s == 0) ? gq : ((s == 1) ? gk : gv);
  const float* bet = (s == 0) ? bq : ((s == 1) ? bk : bv);
  float sc = (s == 1) ? SCALEF * LOG2E : 1.0f;
  for (int i = tid; i < 432; i += 256) wsm[i] = wgt[i];
  if (tid < 48) { gsm[tid] = gam[tid] * sc; bsm[tid] = bet[tid] * sc; }
  __syncthreads();
  int hw = xb * 256 + tid;
  if (hw >= 3136) return;
  int h = hw / 56, w = hw - h * 56;
  const u16* img = qkv + (size_t)sb * (3136 * 48);
  float acc[48];
  #pragma unroll
  for (int c = 0; c < 48; ++c) acc[c] = 0.f;
  #pragma unroll
  for (int dy = -1; dy <= 1; ++dy) {
    int hh = h + dy;
    if ((unsigned)hh >= 56u) continue;
    #pragma unroll
    for (int dx = -1; dx <= 1; ++dx) {
      int ww = w + dx;
      if ((unsigned)ww >= 56u) continue;
      const uint4* p = reinterpret_cast<const uint4*>(img + (size_t)(hh * 56 + ww) * 48);
      const float4* wr = reinterpret_cast<const float4*>(wsm + ((dy + 1) * 3 + (dx + 1)) * 48);
      #pragma unroll
      for (int g = 0; g < 6; ++g) {
        uint4 v = p[g];
        float4 w0 = wr[g * 2], w1 = wr[g * 2 + 1];
        acc[g * 8 + 0] += uasf(v.x << 16)          * w0.x;
        acc[g * 8 + 1] += uasf(v.x & 0xFFFF0000u)  * w0.y;
        acc[g * 8 + 2] += uasf(v.y << 16)          * w0.z;
        acc[g * 8 + 3] += uasf(v.y & 0xFFFF0000u)  * w0.w;
        acc[g * 8 + 4] += uasf(v.z << 16)          * w1.x;
        acc[g * 8 + 5] += uasf(v.z & 0xFFFF0000u)  * w1.y;
        acc[g * 8 + 6] += uasf(v.w << 16)          * w1.z;
        acc[g * 8 + 7] += uasf(v.w & 0xFFFF0000u)  * w1.w;
      }
    }
  }
  float sum = 0.f, ssq = 0.f;
  #pragma unroll
  for (int c = 0; c < 48; ++c) { sum += acc[c]; ssq += acc[c] * acc[c]; }
  float mean = sum * (1.f / 48.f);
  float var = ssq * (1.f / 48.f) - mean * mean;
  float inv = rsqrtf(var + EPSF);
  u16* op = out + ((size_t)sb * 3136 + hw) * 48;
  #pragma unroll
  for (int g = 0; g < 6; ++g) {
    const float4 gm0 = *reinterpret_cast<const float4*>(gsm + g * 8);
    const float4 gm1 = *reinterpret_cast<const float4*>(gsm + g * 8 + 4);
    const float4 bt0 = *reinterpret_cast<const float4*>(bsm + g * 8);
    const float4 bt1 = *reinterpret_cast<const float4*>(bsm + g * 8 + 4);
    uint4 ov;
    u32 a0 = f2b((acc[g * 8 + 0] - mean) * inv * gm0.x + bt0.x);
    u32 a1 = f2b((acc[g * 8 + 1] - mean) * inv * gm0.y + bt0.y);
    u32 a2 = f2b((acc[g * 8 + 2] - mean) * inv * gm0.z + bt0.z);
    u32 a3 = f2b((acc[g * 8 + 3] - mean) * inv * gm0.w + bt0.w);
    u32 a4 = f2b((acc[g * 8 + 4] - mean) * inv * gm1.x + bt1.x);
    u32 a5 = f2b((acc[g * 8 + 5] - mean) * inv * gm1.y + bt1.y);
    u32 a6 = f2b((acc[g * 8 + 6] - mean) * inv * gm1.z + bt1.z);
    u32 a7 = f2b((acc[g * 8 + 7] - mean) * inv * gm1.w + bt1.w);
    ov.x = a0 | (a1 << 16);
    ov.y = a2 | (a3 << 16);
    ov.z = a4 | (a5 << 16);
    ov.w = a6 | (a7 << 16);
    *reinterpret_cast<uint4*>(op + g * 8) = ov;
  }
}

// ---- MFMA window attention, extended-K bias fold, log2-domain softmax ----
// Chunked XCD swizzle: the 16 windows of one head stay on one XCD (shared
// Q/K/V panels L2-local). Scores in log2 domain; raw v_exp_f32.
constexpr int LDP = 256;
constexpr int LDK = 104;
constexpr int LDV = 228;
__global__ __launch_bounds__(512, 1)
void attn_kernel(const u16* __restrict__ qkvc, const float* __restrict__ rel_h,
                 const float* __restrict__ rel_w, u16* __restrict__ obuf) {
  __shared__ __attribute__((aligned(16))) u16 KL[208 * LDK];
  __shared__ __attribute__((aligned(16))) u16 VT[48 * LDV];
  __shared__ __attribute__((aligned(16))) u16 QE[208 * 56];
  __shared__ __attribute__((aligned(16))) u16 PB[8 * 16 * LDP];

  int wid = xcd_chunk(blockIdx.x, gridDim.x);   // same-head windows adjacent
  int bnh = wid >> 4, wrem = wid & 15, wh = wrem >> 2, wwn = wrem & 3;
  int tid = threadIdx.x;
  int wave = tid >> 6, lane = tid & 63;
  int q4 = lane >> 4, r16 = lane & 15;

  { u32* z;
    z = (u32*)KL; for (int i = tid; i < 208 * LDK / 2; i += 512) z[i] = 0;
    z = (u32*)VT; for (int i = tid; i < 48 * LDV / 2; i += 512) z[i] = 0;
    // QRW B-operand reads PB rows 0..63 x cols 0..63 (stride 72); LDS start
    // state undefined; 0*NaN=NaN -> must zero the region.
    z = (u32*)PB; for (int i = tid; i < 64 * 72 / 2; i += 512) z[i] = 0;
  }
  __syncthreads();
  size_t qbase = (size_t)bnh * 3136 * 48;
  size_t kbase = ((size_t)(64 + bnh) * 3136) * 48;
  size_t vbase = ((size_t)(128 + bnh) * 3136) * 48;
  for (int i = tid; i < 196 * 12; i += 512) {
    int r = i / 12, c4 = (i - r * 12) * 4;
    int h = wh * 14 + r / 14, w = wwn * 14 + r % 14;
    size_t g = (size_t)(h * 56 + w) * 48 + c4;
    ushort4 kv = *reinterpret_cast<const ushort4*>(qkvc + kbase + g);
    *reinterpret_cast<ushort4*>(KL + r * LDK + c4) = kv;   // pre-scaled k
    ushort4 vv = *reinterpret_cast<const ushort4*>(qkvc + vbase + g);
    VT[(c4 + 0) * LDV + r] = vv.x; VT[(c4 + 1) * LDV + r] = vv.y;
    VT[(c4 + 2) * LDV + r] = vv.z; VT[(c4 + 3) * LDV + r] = vv.w;
  }
  // K one-hot / mask flag columns (bf16 1.0 = 0x3F80)
  for (int r = tid; r < 208; r += 512) {
    if (r < 196) {
      KL[r * LDK + 48 + r / 14] = 0x3F80;
      KL[r * LDK + 62 + r % 14] = 0x3F80;
    } else {
      KL[r * LDK + 76] = 0x3F80;
    }
  }
  // Rel staged *log2e so QE bias tables are in log2 domain
  for (int i = tid; i < 54 * 48; i += 512) {
    int r = i / 48, c = i - r * 48;
    float v = (r < 27) ? rel_h[r * 48 + c] : rel_w[(r - 27) * 48 + c];
    PB[r * 72 + c] = f2b(v * LOG2E);
  }
  __syncthreads();
  // QE = Q @ Rel^T
  for (int mf = wave; mf < 13; mf += 8) {
    int qrow = mf * 16 + r16; int qc = qrow < 196 ? qrow : 195;
    int hq = wh * 14 + qc / 14, wq = wwn * 14 + qc % 14;
    const u16* qpg = qkvc + qbase + (size_t)(hq * 56 + wq) * 48;
    bf16x8 af0 = *reinterpret_cast<const bf16x8*>(qpg + q4 * 8);
    bf16x8 af1 = {0, 0, 0, 0, 0, 0, 0, 0};
    if (q4 < 2) af1 = *reinterpret_cast<const bf16x8*>(qpg + 32 + q4 * 8);
    #pragma unroll
    for (int nf = 0; nf < 4; ++nf) {
      bf16x8 b0 = *reinterpret_cast<const bf16x8*>(PB + (nf * 16 + r16) * 72 + q4 * 8);
      bf16x8 b1 = *reinterpret_cast<const bf16x8*>(PB + (nf * 16 + r16) * 72 + 32 + q4 * 8);
      f32x4 acc = {};
      acc = MFMA16(af0, b0, acc);
      acc = MFMA16(af1, b1, acc);
      int col = nf * 16 + r16;
      if (col < 54) {
        #pragma unroll
        for (int j = 0; j < 4; ++j)
          QE[(mf * 16 + q4 * 4 + j) * 56 + col] = f2b(acc[j]);
      }
    }
  }
  __syncthreads();
  u16 bhv[14], bwv[14];
  {
    int t = tid;
    if (t < 208) {
      int qc = t < 196 ? t : 195;
      int qh = qc / 14, qw = qc - qh * 14;
      const u16* src = QE + t * 56;
      #pragma unroll
      for (int z = 0; z < 14; ++z) {
        bhv[z] = src[qh + 13 - z];
        bwv[z] = src[27 + qw + 13 - z];
      }
    }
  }
  __syncthreads();
  {
    int t = tid;
    if (t < 208) {
      u16* dst = QE + t * 56;
      #pragma unroll
      for (int z = 0; z < 14; ++z) { dst[z] = bhv[z]; dst[14 + z] = bwv[z]; }
      dst[28] = f2b(-30000.0f);
      #pragma unroll
      for (int z = 29; z < 56; ++z) dst[z] = 0;
    }
  }
  // zero this wave's P-tile pad slots (swizzled positions, XOR q4<<4 scheme)
  u16* Pw = PB + wave * 16 * LDP;
  for (int i = lane; i < 16 * 16; i += 64) {
    int r = i >> 4;
    Pw[r * LDP + ((208 + (i & 15)) ^ (((r >> 2) & 3) << 4))] = 0;
  }
  __syncthreads();
  int bI = bnh >> 3, nhI = bnh & 7;
  for (int mf = wave; mf < 13; mf += 8) {
    int qrow = mf * 16 + r16; int qc = qrow < 196 ? qrow : 195;
    int hq = wh * 14 + qc / 14, wq = wwn * 14 + qc % 14;
    const u16* qpg = qkvc + qbase + (size_t)(hq * 56 + wq) * 48;
    const u16* qe = QE + qrow * 56;
    bf16x8 af0 = *reinterpret_cast<const bf16x8*>(qpg + q4 * 8);
    bf16x8 af1;
    if (q4 < 2) af1 = *reinterpret_cast<const bf16x8*>(qpg + 32 + q4 * 8);
    else        af1 = *reinterpret_cast<const bf16x8*>(qe + (q4 - 2) * 8);
    bf16x8 af2 = *reinterpret_cast<const bf16x8*>(qe + 16 + q4 * 8);
    f32x4 s[13];
    #pragma unroll
    for (int nf = 0; nf < 13; ++nf) {
      const u16* kr = KL + (nf * 16 + r16) * LDK;
      bf16x8 b0 = *reinterpret_cast<const bf16x8*>(kr + q4 * 8);
      bf16x8 b1 = *reinterpret_cast<const bf16x8*>(kr + 32 + q4 * 8);
      bf16x8 b2 = *reinterpret_cast<const bf16x8*>(kr + 64 + q4 * 8);
      f32x4 a = {};
      a = MFMA16(af0, b0, a);
      a = MFMA16(af1, b1, a);
      a = MFMA16(af2, b2, a);
      s[nf] = a;
    }
    int rowb = mf * 16 + q4 * 4;
    float mrow[4], den[4];
    #pragma unroll
    for (int j = 0; j < 4; ++j) {
      float mm = s[0][j];
      #pragma unroll
      for (int nf = 1; nf < 13; ++nf) mm = fmaxf(mm, s[nf][j]);
      #pragma unroll
      for (int off = 1; off < 16; off <<= 1) mm = fmaxf(mm, __shfl_xor(mm, off));
      mrow[j] = mm; den[j] = 0.f;
    }
    #pragma unroll
    for (int nf = 0; nf < 13; ++nf) {
      #pragma unroll
      for (int j = 0; j < 4; ++j) {
        float p = __builtin_amdgcn_exp2f(s[nf][j] - mrow[j]);  // raw v_exp_f32
        den[j] += p;
        Pw[(q4 * 4 + j) * LDP + (((nf * 16 + r16) ^ (q4 << 4)))] = f2b(p);
      }
    }
    #pragma unroll
    for (int j = 0; j < 4; ++j)
      #pragma unroll
      for (int off = 1; off < 16; off <<= 1) den[j] += __shfl_xor(den[j], off);
    f32x4 o[3] = {};
    #pragma unroll
    for (int ks = 0; ks < 7; ++ks) {
      bf16x8 ap = *reinterpret_cast<const bf16x8*>(
          Pw + r16 * LDP + ((ks * 32 + q4 * 8) ^ (((r16 >> 2) & 3) << 4)));
      #pragma unroll
      for (int nf3 = 0; nf3 < 3; ++nf3) {
        bf16x8 bv = *reinterpret_cast<const bf16x8*>(VT + (nf3 * 16 + r16) * LDV + ks * 32 + q4 * 8);
        o[nf3] = MFMA16(ap, bv, o[nf3]);
      }
    }
    #pragma unroll
    for (int j = 0; j < 4; ++j) {
      int row = rowb + j;
      if (row < 196) {
        float rden = 1.f / den[j];
        int rh = row / 14;
        int h = wh * 14 + rh, w = wwn * 14 + row - rh * 14;
        int tok = (bI * 56 + h) * 56 + w;
        const u16* qg = qkvc + qbase + (size_t)(h * 56 + w) * 48;
        #pragma unroll
        for (int nf3 = 0; nf3 < 3; ++nf3) {
          int col = nf3 * 16 + r16;
          int cg = nhI * 48 + col;
          obuf[(size_t)(cg >> 5) * (NTOK * 32) + (size_t)tok * 32 + (cg & 31)] =
              f2b(o[nf3][j] * rden + b2f(qg[col]));
        }
      }
    }
  }
}

extern "C" void kernel_launch(void* const* d_in, const int* in_sizes, int n_in,
                              void* d_out, int out_size, void* d_ws, size_t ws_size,
                              hipStream_t stream) {
  const float* x1      = (const float*)d_in[0];
  const float* x2      = (const float*)d_in[1];
  const float* norm1_w = (const float*)d_in[2];
  const float* norm1_b = (const float*)d_in[3];
  const float* qkv_w   = (const float*)d_in[4];
  const float* qkv_b   = (const float*)d_in[5];
  const float* poolq_w = (const float*)d_in[6];
  const float* poolk_w = (const float*)d_in[7];
  const float* poolv_w = (const float*)d_in[8];
  const float* nq_w    = (const float*)d_in[9];
  const float* nq_b    = (const float*)d_in[10];
  const float* nk_w    = (const float*)d_in[11];
  const float* nk_b    = (const float*)d_in[12];
  const float* nv_w    = (const float*)d_in[13];
  const float* nv_b    = (const float*)d_in[14];
  const float* rel_h   = (const float*)d_in[15];
  const float* rel_w   = (const float*)d_in[16];
  const float* proj_w  = (const float*)d_in[17];
  const float* proj_b  = (const float*)d_in[18];
  const float* norm2_w = (const float*)d_in[19];
  const float* norm2_b = (const float*)d_in[20];
  const float* fc1_w   = (const float*)d_in[21];
  const float* fc1_b   = (const float*)d_in[22];
  const float* fc2_w   = (const float*)d_in[23];
  const float* fc2_b   = (const float*)d_in[24];

  // ws overlay (u16 units). Peak = 57,802,752 u16 = 115.6 MB
  u16* ws      = (u16*)d_ws;
  u16* qkv     = ws;                  // [0, 28901376)   qkv bf16, [3,64,3136,48]
  u16* xn      = ws + 28901376;       // LN(x1) bf16, K-blocked [12][25088][32]
  u16* qkvc    = ws + 28901376;       // post conv+LN (after xn dead)
  u16* obuf    = ws;                  // attn out bf16 K-blocked [12][25088][32]
  u16* h1      = ws;                  // gelu(fc1) bf16 K-blocked [48][25088][32]
  u16* yn      = ws + 48168960;       // LN(y1) bf16 K-blocked [12][25088][32]
  u16* qkv_wt  = ws + 38535168;       // bf16 [1152][384] (dies at step 3)
  u16* proj_wt = ws + 9633792;        // bf16 [384][384]  (after qkv dead)
  u16* fc1_wt  = ws + 38535168;       // bf16 [1536][384] (after qkvc dead)
  u16* fc2_wt  = ws + 39124992;       // bf16 [384][1536]
  float* y1 = (float*)d_out;          // 9633792 f32
  float* y2 = y1 + 9633792;

  // 0a. convert qkv weights (transposed [N][K] bf16)
  wcvt_kernel<<<dim3(12, 36), 256, 0, stream>>>(qkv_w, qkv_wt, 384, 1152);
  // 1. xn = LN(x1)  (K-blocked out)
  ln384_kernel<<<NTOK / 4, 256, 0, stream>>>(x1, norm1_w, norm1_b, xn);
  // 2. qkv = xn @ qkv_w + qkv_b  (BN=64; XCD-chunked)
  mgemm_kernel<0, 64><<<196 * 18, 256, 0, stream>>>(xn, qkv_wt, qkv_b, nullptr, qkv, NTOK, 1152, 384);
  // 3. q/k/v = LN(dwconv3x3(qkv))  (flat grid, XCD-chunked sb-major)
  convln_kernel<<<13 * 192, 256, 0, stream>>>(qkv, poolq_w, poolk_w, poolv_w,
                                              nq_w, nq_b, nk_w, nk_b, nv_w, nv_b, qkvc);
  // 0b. convert proj weights (qkv region now dead)
  wcvt_kernel<<<dim3(12, 12), 256, 0, stream>>>(proj_w, proj_wt, 384, 384);
  // 4. MFMA window attention (XCD-chunked same-head windows), K-blocked obuf
  attn_kernel<<<1024, 512, 0, stream>>>(qkvc, rel_h, rel_w, obuf);
  // 0c. convert mlp weights (qkvc region now dead)
  wcvt_kernel<<<dim3(12, 48), 256, 0, stream>>>(fc1_w, fc1_wt, 384, 1536);
  wcvt_kernel<<<dim3(48, 12), 256, 0, stream>>>(fc2_w, fc2_wt, 1536, 384);
  // 5. y1 = x1 + obuf @ proj_w + proj_b  (BN=64; XCD-chunked)
  mgemm_kernel<1, 64><<<196 * 6, 256, 0, stream>>>(obuf, proj_wt, proj_b, x1, y1, NTOK, 384, 384);
  // 6. yn = LN(y1)  (K-blocked out)
  ln384_kernel<<<NTOK / 4, 256, 0, stream>>>(y1, norm2_w, norm2_b, yn);
  // 7. h1 = gelu(yn @ fc1_w + fc1_b)  (BN=64; K-blocked out; XCD-chunked)
  mgemm_kernel<2, 64><<<196 * 24, 256, 0, stream>>>(yn, fc1_wt, fc1_b, nullptr, h1, NTOK, 1536, 384);
  // 8. y2 = x2 + h1 @ fc2_w + fc2_b  (BN=64; XCD-chunked)
  mgemm_kernel<1, 64><<<196 * 6, 256, 0, stream>>>(h1, fc2_wt, fc2_b, x2, y2, NTOK, 384, 1536);
}